// Round 9
// baseline (399.373 us; speedup 1.0000x reference)
//
#include <hip/hip_runtime.h>
#include <hip/hip_bf16.h>

#define N_NODES 50000
#define N_EDGES 800000
#define HDIM 128
#define NCH 5
#define NB_SCAN ((N_NODES + 255) / 256)  // 196
#define NB_E (N_EDGES / 256)             // 3125 (exact)
#define CUTOFF 10.0f
#define WP_CAP 720000  // Wp row capacity; expected ~400k unmasked (guarded)

typedef float f4 __attribute__((ext_vector_type(4)));
typedef short bf8 __attribute__((ext_vector_type(8)));    // 8 bf16 = MFMA A/B frag
typedef short s8v __attribute__((ext_vector_type(8)));    // raw 8x bf16 bits
typedef float f32x4 __attribute__((ext_vector_type(4)));  // MFMA C/D frag

struct __align__(8) b16x4 { __hip_bfloat16 v[4]; };
struct __align__(16) b16x8 { __hip_bfloat16 v[8]; };

__device__ __forceinline__ float bf2f(short u) {
  return __uint_as_float(((unsigned)(unsigned short)u) << 16);
}
__device__ __forceinline__ short f2bf(float f) {
  return (short)__bfloat16_as_ushort(__float2bfloat16(f));
}

// ---------------- CSR build (split: unmasked / masked; single atomic pass) ------

__global__ void k_count(const int* __restrict__ dst, const float* __restrict__ elen,
                        int* __restrict__ ucnt, int* __restrict__ mcnt,
                        int* __restrict__ rank) {
  int i = blockIdx.x * blockDim.x + threadIdx.x;
  if (i < N_EDGES) {
    int d = dst[i];
    if (elen[i] <= CUTOFF) rank[i] = atomicAdd(&ucnt[d], 1);
    else rank[i] = atomicAdd(&mcnt[d], 1);
  }
}

// joint u+m local scan: blocks [0,NB) -> ucnt/urow, [NB,2NB) -> mcnt/mrow
__global__ __launch_bounds__(256) void k_scan_local(
    const int* __restrict__ ucnt, const int* __restrict__ mcnt,
    int* __restrict__ urow, int* __restrict__ mrow, int* __restrict__ bsum) {
  __shared__ int buf[256];
  int b = blockIdx.x, tid = threadIdx.x;
  const int* cnt = (b < NB_SCAN) ? ucnt : mcnt;
  int* row = (b < NB_SCAN) ? urow : mrow;
  int i = ((b < NB_SCAN) ? b : b - NB_SCAN) * 256 + tid;
  int v = (i < N_NODES) ? cnt[i] : 0;
  buf[tid] = v;
  __syncthreads();
  for (int off = 1; off < 256; off <<= 1) {
    int t = (tid >= off) ? buf[tid - off] : 0;
    __syncthreads();
    buf[tid] += t;
    __syncthreads();
  }
  if (i < N_NODES) row[i] = buf[tid] - v;  // local exclusive
  if (tid == 255) bsum[b] = buf[255];
}

// joint top scan over 2*NB block sums (m prefixes come out pre-offset by nUm)
__global__ __launch_bounds__(256) void k_scan_top(const int* __restrict__ bsum,
                                                  int* __restrict__ boff) {
  __shared__ int buf[256];
  int tid = threadIdx.x;
  int run = 0;
  for (int base = 0; base < 2 * NB_SCAN; base += 256) {
    int i = base + tid;
    int v = (i < 2 * NB_SCAN) ? bsum[i] : 0;
    buf[tid] = v;
    __syncthreads();
    for (int off = 1; off < 256; off <<= 1) {
      int t = (tid >= off) ? buf[tid - off] : 0;
      __syncthreads();
      buf[tid] += t;
      __syncthreads();
    }
    if (i < 2 * NB_SCAN) boff[i] = run + buf[tid] - v;
    run += buf[255];
    __syncthreads();
  }
  if (tid == 0) boff[2 * NB_SCAN] = run;  // = N_EDGES
}

__global__ __launch_bounds__(256) void k_scan_add(int* __restrict__ urow,
                                                  int* __restrict__ mrow,
                                                  const int* __restrict__ boff) {
  int b = blockIdx.x, tid = threadIdx.x;
  int* row = (b < NB_SCAN) ? urow : mrow;
  int i = ((b < NB_SCAN) ? b : b - NB_SCAN) * 256 + tid;
  if (i < N_NODES) row[i] += boff[b];
  if (tid == 0 && b == 0) urow[N_NODES] = boff[NB_SCAN];            // nUm
  if (tid == 0 && b == NB_SCAN) mrow[N_NODES] = boff[2 * NB_SCAN];  // N_EDGES
}

// atomic-free scatter: slot = row[dst] + rank -> esrc2
__global__ void k_scatter(const int* __restrict__ src, const int* __restrict__ dst,
                          const float* __restrict__ elen,
                          const int* __restrict__ urow, const int* __restrict__ mrow,
                          const int* __restrict__ rank, int* __restrict__ esrc2) {
  int i = blockIdx.x * blockDim.x + threadIdx.x;
  if (i < N_EDGES) {
    int d = dst[i];
    if (elen[i] <= CUTOFF) esrc2[urow[d] + rank[i]] = src[i];
    else esrc2[mrow[d] + rank[i]] = src[i];
  }
}

// ---------------- ascending-id compaction of unmasked edges ---------------------
// elist[j] = j-th unmasked edge id (ascending); upos[j] = its CSR slot.

__global__ __launch_bounds__(256) void k_escan_local(const float* __restrict__ elen,
                                                     int* __restrict__ eloc,
                                                     int* __restrict__ ebsum) {
  __shared__ int buf[256];
  int b = blockIdx.x, tid = threadIdx.x, i = b * 256 + tid;
  int v = (elen[i] <= CUTOFF) ? 1 : 0;
  buf[tid] = v;
  __syncthreads();
  for (int off = 1; off < 256; off <<= 1) {
    int t = (tid >= off) ? buf[tid - off] : 0;
    __syncthreads();
    buf[tid] += t;
    __syncthreads();
  }
  eloc[i] = buf[tid] - v;
  if (tid == 255) ebsum[b] = buf[255];
}

__global__ __launch_bounds__(256) void k_escan_top(const int* __restrict__ ebsum,
                                                   int* __restrict__ eboff) {
  __shared__ int buf[256];
  int tid = threadIdx.x;
  int run = 0;
  for (int base = 0; base < NB_E; base += 256) {
    int i = base + tid;
    int v = (i < NB_E) ? ebsum[i] : 0;
    buf[tid] = v;
    __syncthreads();
    for (int off = 1; off < 256; off <<= 1) {
      int t = (tid >= off) ? buf[tid - off] : 0;
      __syncthreads();
      buf[tid] += t;
      __syncthreads();
    }
    if (i < NB_E) eboff[i] = run + buf[tid] - v;
    run += buf[255];
    __syncthreads();
  }
  if (tid == 0) eboff[NB_E] = run;  // nUnmasked
}

__global__ __launch_bounds__(256) void k_ecompact(
    const float* __restrict__ elen, const int* __restrict__ eloc,
    const int* __restrict__ eboff, const int* __restrict__ dst,
    const int* __restrict__ rank, const int* __restrict__ urow,
    int* __restrict__ elist, int* __restrict__ upos) {
  int b = blockIdx.x, i = b * 256 + threadIdx.x;
  if (elen[i] <= CUTOFF) {
    int j = eboff[b] + eloc[i];
    elist[j] = i;
    upos[j] = urow[dst[i]] + rank[i];
  }
}

// ---------------- weight repack for MFMA B-fragments (all 4 mats, one launch) ---
// wp[((jt*4+kk)*64 + l)*8 + j] = bf16( w[(kk*32 + (l>>4)*8 + j)*128 + jt*16 + (l&15)] )

__global__ __launch_bounds__(256) void k_repack4(
    const float* __restrict__ wA, const float* __restrict__ wB,
    const float* __restrict__ wC, const float* __restrict__ wD,
    __hip_bfloat16* __restrict__ wp) {  // wp: 4 packs of 16384 bf16
  int gid = blockIdx.x;                 // 0..31: mat = gid>>3
  const float* w = (gid < 8) ? wA : (gid < 16) ? wB : (gid < 24) ? wC : wD;
  int idx = (gid & 7) * 256 + threadIdx.x;  // 0..2047 within mat
  int l = idx & 63;
  int f = idx >> 6;
  int kk = f & 3, jt = f >> 2;
  int col = jt * 16 + (l & 15);
  int kb = kk * 32 + (l >> 4) * 8;
  b16x8 o;
#pragma unroll
  for (int j = 0; j < 8; ++j) o.v[j] = __float2bfloat16(w[(kb + j) * HDIM + col]);
  *reinterpret_cast<b16x8*>(&wp[(size_t)(gid >> 3) * 16384 + idx * 8]) = o;
}

// ---------------- f32 4x4-tile GEMM (node_emb only) --------

__device__ __forceinline__ void tile_gemm(const float (*in)[129],
                                          const float* __restrict__ wmat,
                                          const float* __restrict__ bias,
                                          int r4, int jb, float acc[4][4]) {
  f4 bv = *reinterpret_cast<const f4*>(&bias[jb]);
#pragma unroll
  for (int ii = 0; ii < 4; ++ii)
#pragma unroll
    for (int jj = 0; jj < 4; ++jj) acc[ii][jj] = bv[jj];
#pragma unroll 4
  for (int k = 0; k < HDIM; ++k) {
    f4 wv = *reinterpret_cast<const f4*>(&wmat[k * HDIM + jb]);
    float a0 = in[r4 + 0][k];
    float a1 = in[r4 + 1][k];
    float a2 = in[r4 + 2][k];
    float a3 = in[r4 + 3][k];
#pragma unroll
    for (int jj = 0; jj < 4; ++jj) {
      acc[0][jj] += a0 * wv[jj];
      acc[1][jj] += a1 * wv[jj];
      acc[2][jj] += a2 * wv[jj];
      acc[3][jj] += a3 * wv[jj];
    }
  }
}

// ---------------- node embedding -> hb (bf16 master) ----------------

__global__ __launch_bounds__(256) void k_node_emb(
    const float* __restrict__ z, const float* __restrict__ w0a,
    const float* __restrict__ b0a, const float* __restrict__ w0b,
    const float* __restrict__ b0b, __hip_bfloat16* __restrict__ hb) {
  __shared__ float zs[32][NCH];
  __shared__ float w0as[NCH][HDIM];
  __shared__ float hs[32][129];
  int tid = threadIdx.x;
  int r0 = blockIdx.x * 32;

  for (int i = tid; i < NCH * HDIM; i += 256) w0as[i / HDIM][i % HDIM] = w0a[i];
  for (int i = tid; i < 32 * NCH; i += 256) {
    int r = i / NCH, c = i % NCH;
    int gr = r0 + r;
    zs[r][c] = (gr < N_NODES) ? z[gr * NCH + c] : 0.f;
  }
  __syncthreads();

  for (int i = tid; i < 32 * HDIM; i += 256) {
    int j = i & (HDIM - 1), r = i >> 7;
    float a = b0a[j];
#pragma unroll
    for (int c = 0; c < NCH; ++c) a += zs[r][c] * w0as[c][j];
    hs[r][j] = fmaxf(a, 0.f);
  }
  __syncthreads();

  int cg = tid & 31, rg = tid >> 5;
  int jb = cg * 4, r4 = rg * 4;
  float acc[4][4];
  tile_gemm(hs, w0b, b0b, r4, jb, acc);

#pragma unroll
  for (int ii = 0; ii < 4; ++ii) {
    int gr = r0 + r4 + ii;
    if (gr < N_NODES) {
      b16x4 ob;
#pragma unroll
      for (int jj = 0; jj < 4; ++jj) ob.v[jj] = __float2bfloat16(acc[ii][jj]);
      *reinterpret_cast<b16x4*>(&hb[(size_t)gr * HDIM + jb]) = ob;
    }
  }
}

// ---------------- edge gate via MFMA, ascending edge-id order -------------------
// Block b handles elist[64b..64b+64): attr reads ascend (near-stream); Wp rows
// scatter to upos (write combining absorbs).

#define SWZ(row, colByte) ((row) * 256 + ((colByte) ^ (((row) & 7) << 4)))

__global__ __launch_bounds__(256) void k_edge_gate_mfma(
    const float* __restrict__ attr, const __hip_bfloat16* __restrict__ w2aP,
    const float* __restrict__ b2a, const __hip_bfloat16* __restrict__ w2bP,
    const float* __restrict__ b2b, const int* __restrict__ elist,
    const int* __restrict__ upos, const int* __restrict__ nUmPtr,
    __hip_bfloat16* __restrict__ Wp) {
  __shared__ char sA[64 * 256];  // 64 x 128 bf16, swizzled (reused 3x)
  __shared__ int sEid[64];
  __shared__ int sSlot[64];
  const int tid = threadIdx.x;
  const int wv = tid >> 6, l = tid & 63;
  const int e0 = blockIdx.x * 64;
  const int nUm = nUmPtr[0];
  if (e0 >= nUm) return;

  if (tid < 64) {
    int idx = e0 + tid;
    int j = (idx < nUm) ? idx : (nUm - 1);
    sEid[tid] = elist[j];
    sSlot[tid] = upos[j];
  }
  __syncthreads();

  // stage attr rows (ascending ids) -> sA bf16
#pragma unroll
  for (int i = 0; i < 8; ++i) {
    int c = tid + i * 256;
    int row = c >> 5, col4 = (c & 31) * 4;
    f4 v = *reinterpret_cast<const f4*>(&attr[(size_t)sEid[row] * HDIM + col4]);
    b16x4 o;
    o.v[0] = __float2bfloat16(v[0]);
    o.v[1] = __float2bfloat16(v[1]);
    o.v[2] = __float2bfloat16(v[2]);
    o.v[3] = __float2bfloat16(v[3]);
    *reinterpret_cast<b16x4*>(&sA[SWZ(row, col4 * 2)]) = o;
  }

  bf8 B1[2][4], B2[2][4];
#pragma unroll
  for (int nt = 0; nt < 2; ++nt)
#pragma unroll
    for (int kk = 0; kk < 4; ++kk) {
      int f = (2 * wv + nt) * 4 + kk;
      B1[nt][kk] = *reinterpret_cast<const bf8*>(&w2aP[(f * 64 + l) * 8]);
      B2[nt][kk] = *reinterpret_cast<const bf8*>(&w2bP[(f * 64 + l) * 8]);
    }

  __syncthreads();

  // layer 1
  f32x4 acc[4][2];
  float bias[2];
#pragma unroll
  for (int nt = 0; nt < 2; ++nt) bias[nt] = b2a[(2 * wv + nt) * 16 + (l & 15)];
#pragma unroll
  for (int mt = 0; mt < 4; ++mt)
#pragma unroll
    for (int nt = 0; nt < 2; ++nt)
      acc[mt][nt] = (f32x4){bias[nt], bias[nt], bias[nt], bias[nt]};

#pragma unroll
  for (int kk = 0; kk < 4; ++kk)
#pragma unroll
    for (int mt = 0; mt < 4; ++mt) {
      int row = mt * 16 + (l & 15);
      int kByte = (kk * 32 + (l >> 4) * 8) * 2;
      bf8 a = *reinterpret_cast<const bf8*>(&sA[SWZ(row, kByte)]);
#pragma unroll
      for (int nt = 0; nt < 2; ++nt)
        acc[mt][nt] = __builtin_amdgcn_mfma_f32_16x16x32_bf16(a, B1[nt][kk],
                                                              acc[mt][nt], 0, 0, 0);
    }
  __syncthreads();  // all sA reads done; safe to overwrite

  // hidden = relu(acc) -> sA
#pragma unroll
  for (int mt = 0; mt < 4; ++mt)
#pragma unroll
    for (int nt = 0; nt < 2; ++nt) {
      int colb = ((2 * wv + nt) * 16 + (l & 15)) * 2;
#pragma unroll
      for (int i = 0; i < 4; ++i) {
        int row = mt * 16 + (l >> 4) * 4 + i;
        *reinterpret_cast<__hip_bfloat16*>(&sA[SWZ(row, colb)]) =
            __float2bfloat16(fmaxf(acc[mt][nt][i], 0.f));
      }
    }
  __syncthreads();

  // layer 2
#pragma unroll
  for (int nt = 0; nt < 2; ++nt) bias[nt] = b2b[(2 * wv + nt) * 16 + (l & 15)];
#pragma unroll
  for (int mt = 0; mt < 4; ++mt)
#pragma unroll
    for (int nt = 0; nt < 2; ++nt)
      acc[mt][nt] = (f32x4){bias[nt], bias[nt], bias[nt], bias[nt]};

#pragma unroll
  for (int kk = 0; kk < 4; ++kk)
#pragma unroll
    for (int mt = 0; mt < 4; ++mt) {
      int row = mt * 16 + (l & 15);
      int kByte = (kk * 32 + (l >> 4) * 8) * 2;
      bf8 a = *reinterpret_cast<const bf8*>(&sA[SWZ(row, kByte)]);
#pragma unroll
      for (int nt = 0; nt < 2; ++nt)
        acc[mt][nt] = __builtin_amdgcn_mfma_f32_16x16x32_bf16(a, B2[nt][kk],
                                                              acc[mt][nt], 0, 0, 0);
    }
  __syncthreads();  // all layer-2 sA reads done

  // output -> sA
#pragma unroll
  for (int mt = 0; mt < 4; ++mt)
#pragma unroll
    for (int nt = 0; nt < 2; ++nt) {
      int colb = ((2 * wv + nt) * 16 + (l & 15)) * 2;
#pragma unroll
      for (int i = 0; i < 4; ++i) {
        int row = mt * 16 + (l >> 4) * 4 + i;
        *reinterpret_cast<__hip_bfloat16*>(&sA[SWZ(row, colb)]) =
            __float2bfloat16(acc[mt][nt][i]);
      }
    }
  __syncthreads();

  // scatter rows to CSR slots (256 B contiguous per row), tail-guarded
#pragma unroll
  for (int i = 0; i < 4; ++i) {
    int c = tid + i * 256;
    int row = c >> 4, colc = c & 15;
    if (e0 + row < nUm) {
      int slot = sSlot[row];
      if (slot < WP_CAP) {
        b16x8 v = *reinterpret_cast<const b16x8*>(&sA[SWZ(row, colc * 16)]);
        *reinterpret_cast<b16x8*>(&Wp[(size_t)slot * HDIM + colc * 8]) = v;
      }
    }
  }
}

// ---------------- aggregate: sequential nodes, streamed Wp, 8-wide batches ------
// agg_b[n] = bf16( sum_u relu(hb[src]+Wp[p]) + sum_m relu(hb[src]) )

__global__ __launch_bounds__(256) void k_aggregate(
    const __hip_bfloat16* __restrict__ hb, const __hip_bfloat16* __restrict__ Wp,
    const int* __restrict__ urow, const int* __restrict__ mrow,
    const int* __restrict__ esrc2, __hip_bfloat16* __restrict__ agg_b) {
  int tid = threadIdx.x;
  int node = blockIdx.x * 16 + (tid >> 4);
  if (node >= N_NODES) return;
  const int lane16 = tid & 15;
  const int grpBase = tid & 48;  // group's base lane within the 64-lane wave
  const int c8 = lane16 * 8;

  float s[8];
#pragma unroll
  for (int q = 0; q < 8; ++q) s[q] = 0.f;

  // ---- unmasked edges: hb gather + Wp stream (8 rows in flight)
  int ub = urow[node], ueFull = urow[node + 1];
  int ue = min(ueFull, WP_CAP);
  for (int p0 = ub; p0 < ue; p0 += 16) {
    int cnt = ue - p0;
    if (cnt > 16) cnt = 16;
    int idx = (lane16 < cnt) ? esrc2[p0 + lane16] : 0;
    for (int j = 0; j < cnt; j += 8) {
      s8v hv[8], wv[8];
#pragma unroll
      for (int t = 0; t < 8; ++t) {
        int sr = __shfl(idx, grpBase + j + t, 64);
        if (j + t < cnt) {
          hv[t] = *reinterpret_cast<const s8v*>(&hb[(size_t)sr * HDIM + c8]);
          wv[t] = *reinterpret_cast<const s8v*>(&Wp[(size_t)(p0 + j + t) * HDIM + c8]);
        } else {
          hv[t] = (s8v)0;
          wv[t] = (s8v)0;
        }
      }
#pragma unroll
      for (int t = 0; t < 8; ++t)
#pragma unroll
        for (int q = 0; q < 8; ++q)
          s[q] += fmaxf(bf2f(hv[t][q]) + bf2f(wv[t][q]), 0.f);
    }
  }
  for (int p = ue; p < ueFull; ++p) {  // WP_CAP overflow guard (never in practice)
    int sr = esrc2[p];
    s8v hv = *reinterpret_cast<const s8v*>(&hb[(size_t)sr * HDIM + c8]);
#pragma unroll
    for (int q = 0; q < 8; ++q) s[q] += fmaxf(bf2f(hv[q]), 0.f);
  }

  // ---- masked edges: relu(hb) only (8 rows in flight)
  int mb = mrow[node], me = mrow[node + 1];
  for (int p0 = mb; p0 < me; p0 += 16) {
    int cnt = me - p0;
    if (cnt > 16) cnt = 16;
    int idx = (lane16 < cnt) ? esrc2[p0 + lane16] : 0;
    for (int j = 0; j < cnt; j += 8) {
      s8v hv[8];
#pragma unroll
      for (int t = 0; t < 8; ++t) {
        int sr = __shfl(idx, grpBase + j + t, 64);
        if (j + t < cnt)
          hv[t] = *reinterpret_cast<const s8v*>(&hb[(size_t)sr * HDIM + c8]);
        else
          hv[t] = (s8v)0;
      }
#pragma unroll
      for (int t = 0; t < 8; ++t)
#pragma unroll
        for (int q = 0; q < 8; ++q) s[q] += fmaxf(bf2f(hv[t][q]), 0.f);
    }
  }

  s8v o;
#pragma unroll
  for (int q = 0; q < 8; ++q) o[q] = f2bf(s[q]);
  *reinterpret_cast<s8v*>(&agg_b[(size_t)node * HDIM + c8]) = o;
}

// ---------------- update via MFMA: hb += act(MLP1(agg + hb)); last -> f32 out ---
// Vectorized epilogue: act(out) routed through sA, hb re-read as 16B chunks.

__global__ __launch_bounds__(256) void k_update_mfma(
    const __hip_bfloat16* __restrict__ agg_b,
    const __hip_bfloat16* __restrict__ w1aP, const float* __restrict__ b1a,
    const __hip_bfloat16* __restrict__ w1bP, const float* __restrict__ b1b,
    __hip_bfloat16* __restrict__ hb, float* __restrict__ hout, int is_last) {
  __shared__ char sA[64 * 256];  // 64 x 128 bf16, swizzled (reused)
  const int tid = threadIdx.x;
  const int wv = tid >> 6, l = tid & 63;
  const int r0 = blockIdx.x * 64;

  // stage bf16(agg + hb) -> sA   (1024 16B-chunks)
#pragma unroll
  for (int i = 0; i < 4; ++i) {
    int c = tid + i * 256;
    int row = c >> 4, col8 = (c & 15) * 8;
    int gr = r0 + row;
    s8v o = (s8v)0;
    if (gr < N_NODES) {
      s8v a = *reinterpret_cast<const s8v*>(&agg_b[(size_t)gr * HDIM + col8]);
      s8v hh = *reinterpret_cast<const s8v*>(&hb[(size_t)gr * HDIM + col8]);
#pragma unroll
      for (int q = 0; q < 8; ++q) o[q] = f2bf(bf2f(a[q]) + bf2f(hh[q]));
    }
    *reinterpret_cast<s8v*>(&sA[SWZ(row, col8 * 2)]) = o;
  }

  bf8 B1[2][4], B2[2][4];
#pragma unroll
  for (int nt = 0; nt < 2; ++nt)
#pragma unroll
    for (int kk = 0; kk < 4; ++kk) {
      int f = (2 * wv + nt) * 4 + kk;
      B1[nt][kk] = *reinterpret_cast<const bf8*>(&w1aP[(f * 64 + l) * 8]);
      B2[nt][kk] = *reinterpret_cast<const bf8*>(&w1bP[(f * 64 + l) * 8]);
    }

  __syncthreads();

  // layer 1
  f32x4 acc[4][2];
  float bias[2];
#pragma unroll
  for (int nt = 0; nt < 2; ++nt) bias[nt] = b1a[(2 * wv + nt) * 16 + (l & 15)];
#pragma unroll
  for (int mt = 0; mt < 4; ++mt)
#pragma unroll
    for (int nt = 0; nt < 2; ++nt)
      acc[mt][nt] = (f32x4){bias[nt], bias[nt], bias[nt], bias[nt]};

#pragma unroll
  for (int kk = 0; kk < 4; ++kk)
#pragma unroll
    for (int mt = 0; mt < 4; ++mt) {
      int rowi = mt * 16 + (l & 15);
      int kByte = (kk * 32 + (l >> 4) * 8) * 2;
      bf8 a = *reinterpret_cast<const bf8*>(&sA[SWZ(rowi, kByte)]);
#pragma unroll
      for (int nt = 0; nt < 2; ++nt)
        acc[mt][nt] = __builtin_amdgcn_mfma_f32_16x16x32_bf16(a, B1[nt][kk],
                                                              acc[mt][nt], 0, 0, 0);
    }
  __syncthreads();  // all sA reads done

  // hidden -> sA
#pragma unroll
  for (int mt = 0; mt < 4; ++mt)
#pragma unroll
    for (int nt = 0; nt < 2; ++nt) {
      int colb = ((2 * wv + nt) * 16 + (l & 15)) * 2;
#pragma unroll
      for (int i = 0; i < 4; ++i) {
        int rowi = mt * 16 + (l >> 4) * 4 + i;
        *reinterpret_cast<__hip_bfloat16*>(&sA[SWZ(rowi, colb)]) =
            __float2bfloat16(fmaxf(acc[mt][nt][i], 0.f));
      }
    }
  __syncthreads();

  // layer 2
#pragma unroll
  for (int nt = 0; nt < 2; ++nt) bias[nt] = b1b[(2 * wv + nt) * 16 + (l & 15)];
#pragma unroll
  for (int mt = 0; mt < 4; ++mt)
#pragma unroll
    for (int nt = 0; nt < 2; ++nt)
      acc[mt][nt] = (f32x4){bias[nt], bias[nt], bias[nt], bias[nt]};

#pragma unroll
  for (int kk = 0; kk < 4; ++kk)
#pragma unroll
    for (int mt = 0; mt < 4; ++mt) {
      int rowi = mt * 16 + (l & 15);
      int kByte = (kk * 32 + (l >> 4) * 8) * 2;
      bf8 a = *reinterpret_cast<const bf8*>(&sA[SWZ(rowi, kByte)]);
#pragma unroll
      for (int nt = 0; nt < 2; ++nt)
        acc[mt][nt] = __builtin_amdgcn_mfma_f32_16x16x32_bf16(a, B2[nt][kk],
                                                              acc[mt][nt], 0, 0, 0);
    }
  __syncthreads();  // all layer-2 sA reads done

  // act(out) -> sA (bf16); last conv keeps raw (no relu)
#pragma unroll
  for (int mt = 0; mt < 4; ++mt)
#pragma unroll
    for (int nt = 0; nt < 2; ++nt) {
      int colb = ((2 * wv + nt) * 16 + (l & 15)) * 2;
#pragma unroll
      for (int i = 0; i < 4; ++i) {
        int rowi = mt * 16 + (l >> 4) * 4 + i;
        float t = acc[mt][nt][i];
        if (!is_last) t = fmaxf(t, 0.f);
        *reinterpret_cast<__hip_bfloat16*>(&sA[SWZ(rowi, colb)]) =
            __float2bfloat16(t);
      }
    }
  __syncthreads();

  // vector epilogue: nh = hb + t; last conv -> f32 d_out, else -> hb
#pragma unroll
  for (int i = 0; i < 4; ++i) {
    int c = tid + i * 256;
    int row = c >> 4, col8 = (c & 15) * 8;
    int gr = r0 + row;
    if (gr < N_NODES) {
      s8v tv = *reinterpret_cast<const s8v*>(&sA[SWZ(row, col8 * 2)]);
      s8v hh = *reinterpret_cast<const s8v*>(&hb[(size_t)gr * HDIM + col8]);
      if (is_last) {
        f4 o0, o1;
#pragma unroll
        for (int q = 0; q < 4; ++q) o0[q] = bf2f(hh[q]) + bf2f(tv[q]);
#pragma unroll
        for (int q = 0; q < 4; ++q) o1[q] = bf2f(hh[q + 4]) + bf2f(tv[q + 4]);
        *reinterpret_cast<f4*>(&hout[(size_t)gr * HDIM + col8]) = o0;
        *reinterpret_cast<f4*>(&hout[(size_t)gr * HDIM + col8 + 4]) = o1;
      } else {
        s8v o;
#pragma unroll
        for (int q = 0; q < 8; ++q) o[q] = f2bf(bf2f(hh[q]) + bf2f(tv[q]));
        *reinterpret_cast<s8v*>(&hb[(size_t)gr * HDIM + col8]) = o;
      }
    }
  }
}

// ---------------- launch --------------------------------------------------------

extern "C" void kernel_launch(void* const* d_in, const int* in_sizes, int n_in,
                              void* d_out, int out_size, void* d_ws, size_t ws_size,
                              hipStream_t stream) {
  const float* z = (const float*)d_in[0];
  const int* ei = (const int*)d_in[1];
  const float* attr = (const float*)d_in[2];
  const float* elen = (const float*)d_in[3];
  const float* w0a = (const float*)d_in[4];
  const float* b0a = (const float*)d_in[5];
  const float* w0b = (const float*)d_in[6];
  const float* b0b = (const float*)d_in[7];
  const float* w1a = (const float*)d_in[8];
  const float* b1a = (const float*)d_in[9];
  const float* w1b = (const float*)d_in[10];
  const float* b1b = (const float*)d_in[11];
  const float* w2a = (const float*)d_in[12];
  const float* b2a = (const float*)d_in[13];
  const float* w2b = (const float*)d_in[14];
  const float* b2b = (const float*)d_in[15];

  float* hout = (float*)d_out;

  char* ws = (char*)d_ws;
  size_t off = 0;
  __hip_bfloat16* Wp = (__hip_bfloat16*)(ws + off);
  off += (size_t)WP_CAP * HDIM * 2;           // 184.3 MB
  __hip_bfloat16* agg_b = (__hip_bfloat16*)(ws + off);
  off += (size_t)N_NODES * HDIM * 2;          // 12.8 MB
  __hip_bfloat16* hb = (__hip_bfloat16*)(ws + off);
  off += (size_t)N_NODES * HDIM * 2;          // 12.8 MB
  int* esrc2 = (int*)(ws + off);
  off += (size_t)N_EDGES * 4;                 // 3.2 MB
  int* rank = (int*)(ws + off);
  off += (size_t)N_EDGES * 4;                 // 3.2 MB
  int* eloc = (int*)(ws + off);
  off += (size_t)N_EDGES * 4;                 // 3.2 MB
  int* elist = (int*)(ws + off);
  off += (size_t)N_EDGES * 4;                 // 3.2 MB
  int* upos = (int*)(ws + off);
  off += (size_t)N_EDGES * 4;                 // 3.2 MB
  int* urow = (int*)(ws + off);
  off += (size_t)(N_NODES + 64) * 4;
  int* mrow = (int*)(ws + off);
  off += (size_t)(N_NODES + 64) * 4;
  // zero-init region: [ucnt][mcnt] — one memset
  int* ucnt = (int*)(ws + off);
  off += (size_t)N_NODES * 4;
  int* mcnt = (int*)(ws + off);
  off += (size_t)N_NODES * 4;
  int* bsum = (int*)(ws + off);
  off += (size_t)(2 * NB_SCAN + 8) * 4;
  int* boff = (int*)(ws + off);
  off += (size_t)(2 * NB_SCAN + 8) * 4;
  int* ebsum = (int*)(ws + off);
  off += (size_t)(NB_E + 8) * 4;
  int* eboff = (int*)(ws + off);
  off += (size_t)(NB_E + 8) * 4;
  __hip_bfloat16* wPk = (__hip_bfloat16*)(ws + off);  // [w2a|w2b|w1a|w1b] packs
  off += (size_t)4 * HDIM * HDIM * 2;                 // 128 KB  (total ~227 MB)
  __hip_bfloat16* w2aP = wPk;
  __hip_bfloat16* w2bP = wPk + 16384;
  __hip_bfloat16* w1aP = wPk + 2 * 16384;
  __hip_bfloat16* w1bP = wPk + 3 * 16384;

  const int* src = ei;
  const int* dst = ei + N_EDGES;

  // split CSR build (single atomic pass)
  hipMemsetAsync(ucnt, 0, (size_t)(2 * N_NODES) * 4, stream);
  k_count<<<(N_EDGES + 255) / 256, 256, 0, stream>>>(dst, elen, ucnt, mcnt, rank);
  k_scan_local<<<2 * NB_SCAN, 256, 0, stream>>>(ucnt, mcnt, urow, mrow, bsum);
  k_scan_top<<<1, 256, 0, stream>>>(bsum, boff);
  k_scan_add<<<2 * NB_SCAN, 256, 0, stream>>>(urow, mrow, boff);
  k_scatter<<<(N_EDGES + 255) / 256, 256, 0, stream>>>(src, dst, elen, urow, mrow,
                                                       rank, esrc2);

  // ascending-id compaction of unmasked edges (elist + target slot upos)
  k_escan_local<<<NB_E, 256, 0, stream>>>(elen, eloc, ebsum);
  k_escan_top<<<1, 256, 0, stream>>>(ebsum, eboff);
  k_ecompact<<<NB_E, 256, 0, stream>>>(elen, eloc, eboff, dst, rank, urow, elist,
                                       upos);

  // weight repacks (one launch)
  k_repack4<<<32, 256, 0, stream>>>(w2a, w2b, w1a, w1b, wPk);

  // node embedding -> hb
  k_node_emb<<<(N_NODES + 31) / 32, 256, 0, stream>>>(z, w0a, b0a, w0b, b0b, hb);

  // edge gate over ascending elist (worst-case grid; blocks past nUm exit early)
  k_edge_gate_mfma<<<(N_EDGES + 63) / 64, 256, 0, stream>>>(
      attr, w2aP, b2a, w2bP, b2b, elist, upos, &urow[N_NODES], Wp);

  // convs (bf16 hb master; final conv writes f32 d_out)
  for (int conv = 0; conv < 3; ++conv) {
    k_aggregate<<<(N_NODES + 15) / 16, 256, 0, stream>>>(hb, Wp, urow, mrow, esrc2,
                                                         agg_b);
    k_update_mfma<<<(N_NODES + 63) / 64, 256, 0, stream>>>(
        agg_b, w1aP, b1a, w1bP, b1b, hb, hout, conv == 2 ? 1 : 0);
  }
}

// Round 10
// 376.545 us; speedup vs baseline: 1.0606x; 1.0606x over previous
//
#include <hip/hip_runtime.h>
#include <hip/hip_bf16.h>

#define N_NODES 50000
#define N_EDGES 800000
#define HDIM 128
#define NCH 5
#define NB_SCAN ((N_NODES + 255) / 256)  // 196
#define CUTOFF 10.0f
#define WP_CAP 720000  // Wp row capacity; expected ~400k unmasked (guarded)

typedef float f4 __attribute__((ext_vector_type(4)));
typedef short bf8 __attribute__((ext_vector_type(8)));    // 8 bf16 = MFMA A/B frag
typedef short s8v __attribute__((ext_vector_type(8)));    // raw 8x bf16 bits
typedef float f32x4 __attribute__((ext_vector_type(4)));  // MFMA C/D frag

struct __align__(8) b16x4 { __hip_bfloat16 v[4]; };
struct __align__(16) b16x8 { __hip_bfloat16 v[8]; };

__device__ __forceinline__ float bf2f(short u) {
  return __uint_as_float(((unsigned)(unsigned short)u) << 16);
}
__device__ __forceinline__ short f2bf(float f) {
  return (short)__bfloat16_as_ushort(__float2bfloat16(f));
}

// ---------------- CSR build (split: unmasked / masked; single atomic pass) ------

__global__ void k_count(const int* __restrict__ dst, const float* __restrict__ elen,
                        int* __restrict__ ucnt, int* __restrict__ mcnt,
                        int* __restrict__ rank) {
  int i = blockIdx.x * blockDim.x + threadIdx.x;
  if (i < N_EDGES) {
    int d = dst[i];
    if (elen[i] <= CUTOFF) rank[i] = atomicAdd(&ucnt[d], 1);
    else rank[i] = atomicAdd(&mcnt[d], 1);
  }
}

// joint u+m local scan: blocks [0,NB) -> ucnt/urow, [NB,2NB) -> mcnt/mrow
__global__ __launch_bounds__(256) void k_scan_local(
    const int* __restrict__ ucnt, const int* __restrict__ mcnt,
    int* __restrict__ urow, int* __restrict__ mrow, int* __restrict__ bsum) {
  __shared__ int buf[256];
  int b = blockIdx.x, tid = threadIdx.x;
  const int* cnt = (b < NB_SCAN) ? ucnt : mcnt;
  int* row = (b < NB_SCAN) ? urow : mrow;
  int i = ((b < NB_SCAN) ? b : b - NB_SCAN) * 256 + tid;
  int v = (i < N_NODES) ? cnt[i] : 0;
  buf[tid] = v;
  __syncthreads();
  for (int off = 1; off < 256; off <<= 1) {
    int t = (tid >= off) ? buf[tid - off] : 0;
    __syncthreads();
    buf[tid] += t;
    __syncthreads();
  }
  if (i < N_NODES) row[i] = buf[tid] - v;  // local exclusive
  if (tid == 255) bsum[b] = buf[255];
}

// joint top scan over 2*NB block sums (m prefixes come out pre-offset by nUm)
__global__ __launch_bounds__(256) void k_scan_top(const int* __restrict__ bsum,
                                                  int* __restrict__ boff) {
  __shared__ int buf[256];
  int tid = threadIdx.x;
  int run = 0;
  for (int base = 0; base < 2 * NB_SCAN; base += 256) {
    int i = base + tid;
    int v = (i < 2 * NB_SCAN) ? bsum[i] : 0;
    buf[tid] = v;
    __syncthreads();
    for (int off = 1; off < 256; off <<= 1) {
      int t = (tid >= off) ? buf[tid - off] : 0;
      __syncthreads();
      buf[tid] += t;
      __syncthreads();
    }
    if (i < 2 * NB_SCAN) boff[i] = run + buf[tid] - v;
    run += buf[255];
    __syncthreads();
  }
  if (tid == 0) boff[2 * NB_SCAN] = run;  // = N_EDGES
}

__global__ __launch_bounds__(256) void k_scan_add(int* __restrict__ urow,
                                                  int* __restrict__ mrow,
                                                  const int* __restrict__ boff) {
  int b = blockIdx.x, tid = threadIdx.x;
  int* row = (b < NB_SCAN) ? urow : mrow;
  int i = ((b < NB_SCAN) ? b : b - NB_SCAN) * 256 + tid;
  if (i < N_NODES) row[i] += boff[b];
  if (tid == 0 && b == 0) urow[N_NODES] = boff[NB_SCAN];            // nUm
  if (tid == 0 && b == NB_SCAN) mrow[N_NODES] = boff[2 * NB_SCAN];  // N_EDGES
}

// atomic-free scatter: slot = row[dst] + rank
__global__ void k_scatter(const int* __restrict__ src, const int* __restrict__ dst,
                          const float* __restrict__ elen,
                          const int* __restrict__ urow, const int* __restrict__ mrow,
                          const int* __restrict__ rank, int* __restrict__ esrc2,
                          int* __restrict__ uedge) {
  int i = blockIdx.x * blockDim.x + threadIdx.x;
  if (i < N_EDGES) {
    int d = dst[i];
    if (elen[i] <= CUTOFF) {
      int p = urow[d] + rank[i];
      esrc2[p] = src[i];
      if (p < WP_CAP) uedge[p] = i;
    } else {
      int q = mrow[d] + rank[i];
      esrc2[q] = src[i];
    }
  }
}

// ---------------- weight repack for MFMA B-fragments (all 4 mats, one launch) ---
// wp[((jt*4+kk)*64 + l)*8 + j] = bf16( w[(kk*32 + (l>>4)*8 + j)*128 + jt*16 + (l&15)] )

__global__ __launch_bounds__(256) void k_repack4(
    const float* __restrict__ wA, const float* __restrict__ wB,
    const float* __restrict__ wC, const float* __restrict__ wD,
    __hip_bfloat16* __restrict__ wp) {  // wp: 4 packs of 16384 bf16
  int gid = blockIdx.x;                 // 0..31: mat = gid>>3
  const float* w = (gid < 8) ? wA : (gid < 16) ? wB : (gid < 24) ? wC : wD;
  int idx = (gid & 7) * 256 + threadIdx.x;  // 0..2047 within mat
  int l = idx & 63;
  int f = idx >> 6;
  int kk = f & 3, jt = f >> 2;
  int col = jt * 16 + (l & 15);
  int kb = kk * 32 + (l >> 4) * 8;
  b16x8 o;
#pragma unroll
  for (int j = 0; j < 8; ++j) o.v[j] = __float2bfloat16(w[(kb + j) * HDIM + col]);
  *reinterpret_cast<b16x8*>(&wp[(size_t)(gid >> 3) * 16384 + idx * 8]) = o;
}

// ---------------- f32 4x4-tile GEMM (node_emb only) --------

__device__ __forceinline__ void tile_gemm(const float (*in)[129],
                                          const float* __restrict__ wmat,
                                          const float* __restrict__ bias,
                                          int r4, int jb, float acc[4][4]) {
  f4 bv = *reinterpret_cast<const f4*>(&bias[jb]);
#pragma unroll
  for (int ii = 0; ii < 4; ++ii)
#pragma unroll
    for (int jj = 0; jj < 4; ++jj) acc[ii][jj] = bv[jj];
#pragma unroll 4
  for (int k = 0; k < HDIM; ++k) {
    f4 wv = *reinterpret_cast<const f4*>(&wmat[k * HDIM + jb]);
    float a0 = in[r4 + 0][k];
    float a1 = in[r4 + 1][k];
    float a2 = in[r4 + 2][k];
    float a3 = in[r4 + 3][k];
#pragma unroll
    for (int jj = 0; jj < 4; ++jj) {
      acc[0][jj] += a0 * wv[jj];
      acc[1][jj] += a1 * wv[jj];
      acc[2][jj] += a2 * wv[jj];
      acc[3][jj] += a3 * wv[jj];
    }
  }
}

// ---------------- node embedding -> hb (bf16 master) ----------------

__global__ __launch_bounds__(256) void k_node_emb(
    const float* __restrict__ z, const float* __restrict__ w0a,
    const float* __restrict__ b0a, const float* __restrict__ w0b,
    const float* __restrict__ b0b, __hip_bfloat16* __restrict__ hb) {
  __shared__ float zs[32][NCH];
  __shared__ float w0as[NCH][HDIM];
  __shared__ float hs[32][129];
  int tid = threadIdx.x;
  int r0 = blockIdx.x * 32;

  for (int i = tid; i < NCH * HDIM; i += 256) w0as[i / HDIM][i % HDIM] = w0a[i];
  for (int i = tid; i < 32 * NCH; i += 256) {
    int r = i / NCH, c = i % NCH;
    int gr = r0 + r;
    zs[r][c] = (gr < N_NODES) ? z[gr * NCH + c] : 0.f;
  }
  __syncthreads();

  for (int i = tid; i < 32 * HDIM; i += 256) {
    int j = i & (HDIM - 1), r = i >> 7;
    float a = b0a[j];
#pragma unroll
    for (int c = 0; c < NCH; ++c) a += zs[r][c] * w0as[c][j];
    hs[r][j] = fmaxf(a, 0.f);
  }
  __syncthreads();

  int cg = tid & 31, rg = tid >> 5;
  int jb = cg * 4, r4 = rg * 4;
  float acc[4][4];
  tile_gemm(hs, w0b, b0b, r4, jb, acc);

#pragma unroll
  for (int ii = 0; ii < 4; ++ii) {
    int gr = r0 + r4 + ii;
    if (gr < N_NODES) {
      b16x4 ob;
#pragma unroll
      for (int jj = 0; jj < 4; ++jj) ob.v[jj] = __float2bfloat16(acc[ii][jj]);
      *reinterpret_cast<b16x4*>(&hb[(size_t)gr * HDIM + jb]) = ob;
    }
  }
}

// ---------------- edge gate via MFMA, uCSR-slot order; single LDS tile ---------

#define SWZ(row, colByte) ((row) * 256 + ((colByte) ^ (((row) & 7) << 4)))

__global__ __launch_bounds__(256) void k_edge_gate_mfma(
    const float* __restrict__ attr, const __hip_bfloat16* __restrict__ w2aP,
    const float* __restrict__ b2a, const __hip_bfloat16* __restrict__ w2bP,
    const float* __restrict__ b2b, const int* __restrict__ uedge,
    const int* __restrict__ nUmPtr, __hip_bfloat16* __restrict__ Wp) {
  __shared__ char sA[64 * 256];  // 64 x 128 bf16, swizzled (reused 3x)
  __shared__ int sEid[64];
  const int tid = threadIdx.x;
  const int wv = tid >> 6, l = tid & 63;
  const int e0 = blockIdx.x * 64;
  const int nUm = min(nUmPtr[0], WP_CAP);
  if (e0 >= nUm) return;

  if (tid < 64) {
    int idx = e0 + tid;
    sEid[tid] = uedge[(idx < nUm) ? idx : (nUm - 1)];
  }
  __syncthreads();

  // stage attr rows (gathered by edge id) -> sA bf16
#pragma unroll
  for (int i = 0; i < 8; ++i) {
    int c = tid + i * 256;
    int row = c >> 5, col4 = (c & 31) * 4;
    f4 v = *reinterpret_cast<const f4*>(&attr[(size_t)sEid[row] * HDIM + col4]);
    b16x4 o;
    o.v[0] = __float2bfloat16(v[0]);
    o.v[1] = __float2bfloat16(v[1]);
    o.v[2] = __float2bfloat16(v[2]);
    o.v[3] = __float2bfloat16(v[3]);
    *reinterpret_cast<b16x4*>(&sA[SWZ(row, col4 * 2)]) = o;
  }

  bf8 B1[2][4], B2[2][4];
#pragma unroll
  for (int nt = 0; nt < 2; ++nt)
#pragma unroll
    for (int kk = 0; kk < 4; ++kk) {
      int f = (2 * wv + nt) * 4 + kk;
      B1[nt][kk] = *reinterpret_cast<const bf8*>(&w2aP[(f * 64 + l) * 8]);
      B2[nt][kk] = *reinterpret_cast<const bf8*>(&w2bP[(f * 64 + l) * 8]);
    }

  __syncthreads();

  // layer 1
  f32x4 acc[4][2];
  float bias[2];
#pragma unroll
  for (int nt = 0; nt < 2; ++nt) bias[nt] = b2a[(2 * wv + nt) * 16 + (l & 15)];
#pragma unroll
  for (int mt = 0; mt < 4; ++mt)
#pragma unroll
    for (int nt = 0; nt < 2; ++nt)
      acc[mt][nt] = (f32x4){bias[nt], bias[nt], bias[nt], bias[nt]};

#pragma unroll
  for (int kk = 0; kk < 4; ++kk)
#pragma unroll
    for (int mt = 0; mt < 4; ++mt) {
      int row = mt * 16 + (l & 15);
      int kByte = (kk * 32 + (l >> 4) * 8) * 2;
      bf8 a = *reinterpret_cast<const bf8*>(&sA[SWZ(row, kByte)]);
#pragma unroll
      for (int nt = 0; nt < 2; ++nt)
        acc[mt][nt] = __builtin_amdgcn_mfma_f32_16x16x32_bf16(a, B1[nt][kk],
                                                              acc[mt][nt], 0, 0, 0);
    }
  __syncthreads();  // all sA reads done; safe to overwrite

  // hidden = relu(acc) -> sA
#pragma unroll
  for (int mt = 0; mt < 4; ++mt)
#pragma unroll
    for (int nt = 0; nt < 2; ++nt) {
      int colb = ((2 * wv + nt) * 16 + (l & 15)) * 2;
#pragma unroll
      for (int i = 0; i < 4; ++i) {
        int row = mt * 16 + (l >> 4) * 4 + i;
        *reinterpret_cast<__hip_bfloat16*>(&sA[SWZ(row, colb)]) =
            __float2bfloat16(fmaxf(acc[mt][nt][i], 0.f));
      }
    }
  __syncthreads();

  // layer 2
#pragma unroll
  for (int nt = 0; nt < 2; ++nt) bias[nt] = b2b[(2 * wv + nt) * 16 + (l & 15)];
#pragma unroll
  for (int mt = 0; mt < 4; ++mt)
#pragma unroll
    for (int nt = 0; nt < 2; ++nt)
      acc[mt][nt] = (f32x4){bias[nt], bias[nt], bias[nt], bias[nt]};

#pragma unroll
  for (int kk = 0; kk < 4; ++kk)
#pragma unroll
    for (int mt = 0; mt < 4; ++mt) {
      int row = mt * 16 + (l & 15);
      int kByte = (kk * 32 + (l >> 4) * 8) * 2;
      bf8 a = *reinterpret_cast<const bf8*>(&sA[SWZ(row, kByte)]);
#pragma unroll
      for (int nt = 0; nt < 2; ++nt)
        acc[mt][nt] = __builtin_amdgcn_mfma_f32_16x16x32_bf16(a, B2[nt][kk],
                                                              acc[mt][nt], 0, 0, 0);
    }
  __syncthreads();  // all layer-2 sA reads done

  // output -> sA
#pragma unroll
  for (int mt = 0; mt < 4; ++mt)
#pragma unroll
    for (int nt = 0; nt < 2; ++nt) {
      int colb = ((2 * wv + nt) * 16 + (l & 15)) * 2;
#pragma unroll
      for (int i = 0; i < 4; ++i) {
        int row = mt * 16 + (l >> 4) * 4 + i;
        *reinterpret_cast<__hip_bfloat16*>(&sA[SWZ(row, colb)]) =
            __float2bfloat16(acc[mt][nt][i]);
      }
    }
  __syncthreads();

  // contiguous store: Wp rows e0..e0+63, tail-guarded
#pragma unroll
  for (int i = 0; i < 4; ++i) {
    int c = tid + i * 256;
    int row = c >> 4, colc = c & 15;
    if (e0 + row < nUm) {
      b16x8 v = *reinterpret_cast<const b16x8*>(&sA[SWZ(row, colc * 16)]);
      *reinterpret_cast<b16x8*>(&Wp[(size_t)(e0 + row) * HDIM + colc * 8]) = v;
    }
  }
}

// ---------------- aggregate: sequential nodes, streamed Wp, bf16 out ------------
// agg_b[n] = bf16( sum_u relu(hb[src]+Wp[p]) + sum_m relu(hb[src]) )

__global__ __launch_bounds__(256) void k_aggregate(
    const __hip_bfloat16* __restrict__ hb, const __hip_bfloat16* __restrict__ Wp,
    const int* __restrict__ urow, const int* __restrict__ mrow,
    const int* __restrict__ esrc2, __hip_bfloat16* __restrict__ agg_b) {
  int tid = threadIdx.x;
  int node = blockIdx.x * 16 + (tid >> 4);
  if (node >= N_NODES) return;
  const int lane16 = tid & 15;
  const int grpBase = tid & 48;  // group's base lane within the 64-lane wave
  const int c8 = lane16 * 8;

  float s[8];
#pragma unroll
  for (int q = 0; q < 8; ++q) s[q] = 0.f;

  // ---- unmasked edges: hb gather + Wp stream
  int ub = urow[node], ueFull = urow[node + 1];
  int ue = min(ueFull, WP_CAP);
  for (int p0 = ub; p0 < ue; p0 += 16) {
    int cnt = ue - p0;
    if (cnt > 16) cnt = 16;
    int idx = (lane16 < cnt) ? esrc2[p0 + lane16] : 0;
    for (int j = 0; j < cnt; j += 4) {
      s8v hv[4], wv[4];
#pragma unroll
      for (int t = 0; t < 4; ++t) {
        int sr = __shfl(idx, grpBase + j + t, 64);
        if (j + t < cnt) {
          hv[t] = *reinterpret_cast<const s8v*>(&hb[(size_t)sr * HDIM + c8]);
          wv[t] = *reinterpret_cast<const s8v*>(&Wp[(size_t)(p0 + j + t) * HDIM + c8]);
        } else {
          hv[t] = (s8v)0;
          wv[t] = (s8v)0;
        }
      }
#pragma unroll
      for (int t = 0; t < 4; ++t)
#pragma unroll
        for (int q = 0; q < 8; ++q)
          s[q] += fmaxf(bf2f(hv[t][q]) + bf2f(wv[t][q]), 0.f);
    }
  }
  for (int p = ue; p < ueFull; ++p) {  // WP_CAP overflow guard (never in practice)
    int sr = esrc2[p];
    s8v hv = *reinterpret_cast<const s8v*>(&hb[(size_t)sr * HDIM + c8]);
#pragma unroll
    for (int q = 0; q < 8; ++q) s[q] += fmaxf(bf2f(hv[q]), 0.f);
  }

  // ---- masked edges: relu(hb) only
  int mb = mrow[node], me = mrow[node + 1];
  for (int p0 = mb; p0 < me; p0 += 16) {
    int cnt = me - p0;
    if (cnt > 16) cnt = 16;
    int idx = (lane16 < cnt) ? esrc2[p0 + lane16] : 0;
    for (int j = 0; j < cnt; j += 4) {
      s8v hv[4];
#pragma unroll
      for (int t = 0; t < 4; ++t) {
        int sr = __shfl(idx, grpBase + j + t, 64);
        if (j + t < cnt)
          hv[t] = *reinterpret_cast<const s8v*>(&hb[(size_t)sr * HDIM + c8]);
        else
          hv[t] = (s8v)0;
      }
#pragma unroll
      for (int t = 0; t < 4; ++t)
#pragma unroll
        for (int q = 0; q < 8; ++q) s[q] += fmaxf(bf2f(hv[t][q]), 0.f);
    }
  }

  s8v o;
#pragma unroll
  for (int q = 0; q < 8; ++q) o[q] = f2bf(s[q]);
  *reinterpret_cast<s8v*>(&agg_b[(size_t)node * HDIM + c8]) = o;
}

// ---------------- update via MFMA: hb += act(MLP1(agg + hb)); last -> f32 out ---
// Vectorized epilogue: act(out) routed through sA, hb re-read as 16B chunks.

__global__ __launch_bounds__(256) void k_update_mfma(
    const __hip_bfloat16* __restrict__ agg_b,
    const __hip_bfloat16* __restrict__ w1aP, const float* __restrict__ b1a,
    const __hip_bfloat16* __restrict__ w1bP, const float* __restrict__ b1b,
    __hip_bfloat16* __restrict__ hb, float* __restrict__ hout, int is_last) {
  __shared__ char sA[64 * 256];  // 64 x 128 bf16, swizzled (reused)
  const int tid = threadIdx.x;
  const int wv = tid >> 6, l = tid & 63;
  const int r0 = blockIdx.x * 64;

  // stage bf16(agg + hb) -> sA   (1024 16B-chunks)
#pragma unroll
  for (int i = 0; i < 4; ++i) {
    int c = tid + i * 256;
    int row = c >> 4, col8 = (c & 15) * 8;
    int gr = r0 + row;
    s8v o = (s8v)0;
    if (gr < N_NODES) {
      s8v a = *reinterpret_cast<const s8v*>(&agg_b[(size_t)gr * HDIM + col8]);
      s8v hh = *reinterpret_cast<const s8v*>(&hb[(size_t)gr * HDIM + col8]);
#pragma unroll
      for (int q = 0; q < 8; ++q) o[q] = f2bf(bf2f(a[q]) + bf2f(hh[q]));
    }
    *reinterpret_cast<s8v*>(&sA[SWZ(row, col8 * 2)]) = o;
  }

  bf8 B1[2][4], B2[2][4];
#pragma unroll
  for (int nt = 0; nt < 2; ++nt)
#pragma unroll
    for (int kk = 0; kk < 4; ++kk) {
      int f = (2 * wv + nt) * 4 + kk;
      B1[nt][kk] = *reinterpret_cast<const bf8*>(&w1aP[(f * 64 + l) * 8]);
      B2[nt][kk] = *reinterpret_cast<const bf8*>(&w1bP[(f * 64 + l) * 8]);
    }

  __syncthreads();

  // layer 1
  f32x4 acc[4][2];
  float bias[2];
#pragma unroll
  for (int nt = 0; nt < 2; ++nt) bias[nt] = b1a[(2 * wv + nt) * 16 + (l & 15)];
#pragma unroll
  for (int mt = 0; mt < 4; ++mt)
#pragma unroll
    for (int nt = 0; nt < 2; ++nt)
      acc[mt][nt] = (f32x4){bias[nt], bias[nt], bias[nt], bias[nt]};

#pragma unroll
  for (int kk = 0; kk < 4; ++kk)
#pragma unroll
    for (int mt = 0; mt < 4; ++mt) {
      int rowi = mt * 16 + (l & 15);
      int kByte = (kk * 32 + (l >> 4) * 8) * 2;
      bf8 a = *reinterpret_cast<const bf8*>(&sA[SWZ(rowi, kByte)]);
#pragma unroll
      for (int nt = 0; nt < 2; ++nt)
        acc[mt][nt] = __builtin_amdgcn_mfma_f32_16x16x32_bf16(a, B1[nt][kk],
                                                              acc[mt][nt], 0, 0, 0);
    }
  __syncthreads();  // all sA reads done

  // hidden -> sA
#pragma unroll
  for (int mt = 0; mt < 4; ++mt)
#pragma unroll
    for (int nt = 0; nt < 2; ++nt) {
      int colb = ((2 * wv + nt) * 16 + (l & 15)) * 2;
#pragma unroll
      for (int i = 0; i < 4; ++i) {
        int rowi = mt * 16 + (l >> 4) * 4 + i;
        *reinterpret_cast<__hip_bfloat16*>(&sA[SWZ(rowi, colb)]) =
            __float2bfloat16(fmaxf(acc[mt][nt][i], 0.f));
      }
    }
  __syncthreads();

  // layer 2
#pragma unroll
  for (int nt = 0; nt < 2; ++nt) bias[nt] = b1b[(2 * wv + nt) * 16 + (l & 15)];
#pragma unroll
  for (int mt = 0; mt < 4; ++mt)
#pragma unroll
    for (int nt = 0; nt < 2; ++nt)
      acc[mt][nt] = (f32x4){bias[nt], bias[nt], bias[nt], bias[nt]};

#pragma unroll
  for (int kk = 0; kk < 4; ++kk)
#pragma unroll
    for (int mt = 0; mt < 4; ++mt) {
      int rowi = mt * 16 + (l & 15);
      int kByte = (kk * 32 + (l >> 4) * 8) * 2;
      bf8 a = *reinterpret_cast<const bf8*>(&sA[SWZ(rowi, kByte)]);
#pragma unroll
      for (int nt = 0; nt < 2; ++nt)
        acc[mt][nt] = __builtin_amdgcn_mfma_f32_16x16x32_bf16(a, B2[nt][kk],
                                                              acc[mt][nt], 0, 0, 0);
    }
  __syncthreads();  // all layer-2 sA reads done

  // act(out) -> sA (bf16); last conv keeps raw (no relu)
#pragma unroll
  for (int mt = 0; mt < 4; ++mt)
#pragma unroll
    for (int nt = 0; nt < 2; ++nt) {
      int colb = ((2 * wv + nt) * 16 + (l & 15)) * 2;
#pragma unroll
      for (int i = 0; i < 4; ++i) {
        int rowi = mt * 16 + (l >> 4) * 4 + i;
        float t = acc[mt][nt][i];
        if (!is_last) t = fmaxf(t, 0.f);
        *reinterpret_cast<__hip_bfloat16*>(&sA[SWZ(rowi, colb)]) =
            __float2bfloat16(t);
      }
    }
  __syncthreads();

  // vector epilogue: nh = hb + t; last conv -> f32 d_out, else -> hb
#pragma unroll
  for (int i = 0; i < 4; ++i) {
    int c = tid + i * 256;
    int row = c >> 4, col8 = (c & 15) * 8;
    int gr = r0 + row;
    if (gr < N_NODES) {
      s8v tv = *reinterpret_cast<const s8v*>(&sA[SWZ(row, col8 * 2)]);
      s8v hh = *reinterpret_cast<const s8v*>(&hb[(size_t)gr * HDIM + col8]);
      if (is_last) {
        f4 o0, o1;
#pragma unroll
        for (int q = 0; q < 4; ++q) o0[q] = bf2f(hh[q]) + bf2f(tv[q]);
#pragma unroll
        for (int q = 0; q < 4; ++q) o1[q] = bf2f(hh[q + 4]) + bf2f(tv[q + 4]);
        *reinterpret_cast<f4*>(&hout[(size_t)gr * HDIM + col8]) = o0;
        *reinterpret_cast<f4*>(&hout[(size_t)gr * HDIM + col8 + 4]) = o1;
      } else {
        s8v o;
#pragma unroll
        for (int q = 0; q < 8; ++q) o[q] = f2bf(bf2f(hh[q]) + bf2f(tv[q]));
        *reinterpret_cast<s8v*>(&hb[(size_t)gr * HDIM + col8]) = o;
      }
    }
  }
}

// ---------------- launch --------------------------------------------------------

extern "C" void kernel_launch(void* const* d_in, const int* in_sizes, int n_in,
                              void* d_out, int out_size, void* d_ws, size_t ws_size,
                              hipStream_t stream) {
  const float* z = (const float*)d_in[0];
  const int* ei = (const int*)d_in[1];
  const float* attr = (const float*)d_in[2];
  const float* elen = (const float*)d_in[3];
  const float* w0a = (const float*)d_in[4];
  const float* b0a = (const float*)d_in[5];
  const float* w0b = (const float*)d_in[6];
  const float* b0b = (const float*)d_in[7];
  const float* w1a = (const float*)d_in[8];
  const float* b1a = (const float*)d_in[9];
  const float* w1b = (const float*)d_in[10];
  const float* b1b = (const float*)d_in[11];
  const float* w2a = (const float*)d_in[12];
  const float* b2a = (const float*)d_in[13];
  const float* w2b = (const float*)d_in[14];
  const float* b2b = (const float*)d_in[15];

  float* hout = (float*)d_out;

  char* ws = (char*)d_ws;
  size_t off = 0;
  __hip_bfloat16* Wp = (__hip_bfloat16*)(ws + off);
  off += (size_t)WP_CAP * HDIM * 2;           // 184.3 MB
  __hip_bfloat16* agg_b = (__hip_bfloat16*)(ws + off);
  off += (size_t)N_NODES * HDIM * 2;          // 12.8 MB
  __hip_bfloat16* hb = (__hip_bfloat16*)(ws + off);
  off += (size_t)N_NODES * HDIM * 2;          // 12.8 MB
  int* esrc2 = (int*)(ws + off);
  off += (size_t)N_EDGES * 4;                 // 3.2 MB
  int* uedge = (int*)(ws + off);
  off += (size_t)WP_CAP * 4;                  // 2.88 MB
  int* rank = (int*)(ws + off);
  off += (size_t)N_EDGES * 4;                 // 3.2 MB
  int* urow = (int*)(ws + off);
  off += (size_t)(N_NODES + 64) * 4;
  int* mrow = (int*)(ws + off);
  off += (size_t)(N_NODES + 64) * 4;
  // zero-init region: [ucnt][mcnt] — one memset
  int* ucnt = (int*)(ws + off);
  off += (size_t)N_NODES * 4;
  int* mcnt = (int*)(ws + off);
  off += (size_t)N_NODES * 4;
  int* bsum = (int*)(ws + off);
  off += (size_t)(2 * NB_SCAN + 8) * 4;
  int* boff = (int*)(ws + off);
  off += (size_t)(2 * NB_SCAN + 8) * 4;
  __hip_bfloat16* wPk = (__hip_bfloat16*)(ws + off);  // [w2a|w2b|w1a|w1b] packs
  off += (size_t)4 * HDIM * HDIM * 2;                 // 128 KB
  __hip_bfloat16* w2aP = wPk;
  __hip_bfloat16* w2bP = wPk + 16384;
  __hip_bfloat16* w1aP = wPk + 2 * 16384;
  __hip_bfloat16* w1bP = wPk + 3 * 16384;

  const int* src = ei;
  const int* dst = ei + N_EDGES;

  // split CSR build (single atomic pass)
  hipMemsetAsync(ucnt, 0, (size_t)(2 * N_NODES) * 4, stream);
  k_count<<<(N_EDGES + 255) / 256, 256, 0, stream>>>(dst, elen, ucnt, mcnt, rank);
  k_scan_local<<<2 * NB_SCAN, 256, 0, stream>>>(ucnt, mcnt, urow, mrow, bsum);
  k_scan_top<<<1, 256, 0, stream>>>(bsum, boff);
  k_scan_add<<<2 * NB_SCAN, 256, 0, stream>>>(urow, mrow, boff);
  k_scatter<<<(N_EDGES + 255) / 256, 256, 0, stream>>>(src, dst, elen, urow, mrow,
                                                       rank, esrc2, uedge);

  // weight repacks (one launch)
  k_repack4<<<32, 256, 0, stream>>>(w2a, w2b, w1a, w1b, wPk);

  // node embedding -> hb
  k_node_emb<<<(N_NODES + 31) / 32, 256, 0, stream>>>(z, w0a, b0a, w0b, b0b, hb);

  // edge gate in uCSR-slot order (worst-case grid; blocks past nUm exit early)
  k_edge_gate_mfma<<<(N_EDGES + 63) / 64, 256, 0, stream>>>(
      attr, w2aP, b2a, w2bP, b2b, uedge, &urow[N_NODES], Wp);

  // convs (bf16 hb master; final conv writes f32 d_out)
  for (int conv = 0; conv < 3; ++conv) {
    k_aggregate<<<(N_NODES + 15) / 16, 256, 0, stream>>>(hb, Wp, urow, mrow, esrc2,
                                                         agg_b);
    k_update_mfma<<<(N_NODES + 63) / 64, 256, 0, stream>>>(
        agg_b, w1aP, b1a, w1bP, b1b, hb, hout, conv == 2 ? 1 : 0);
  }
}

// Round 11
// 353.901 us; speedup vs baseline: 1.1285x; 1.0640x over previous
//
#include <hip/hip_runtime.h>
#include <hip/hip_bf16.h>

#define N_NODES 50000
#define N_EDGES 800000
#define HDIM 128
#define NCH 5
#define NB_SCAN ((N_NODES + 255) / 256)  // 196
#define CUTOFF 10.0f
#define WP_CAP 720000  // Wp row capacity; expected ~400k unmasked (guarded)

typedef float f4 __attribute__((ext_vector_type(4)));
typedef short bf8 __attribute__((ext_vector_type(8)));    // 8 bf16 = MFMA A/B frag
typedef short s8v __attribute__((ext_vector_type(8)));    // raw 8x bf16 bits
typedef float f32x4 __attribute__((ext_vector_type(4)));  // MFMA C/D frag

struct __align__(8) b16x4 { __hip_bfloat16 v[4]; };
struct __align__(16) b16x8 { __hip_bfloat16 v[8]; };

__device__ __forceinline__ float bf2f(short u) {
  return __uint_as_float(((unsigned)(unsigned short)u) << 16);
}
__device__ __forceinline__ short f2bf(float f) {
  return (short)__bfloat16_as_ushort(__float2bfloat16(f));
}

// ---------------- CSR build (split: unmasked / masked; single atomic pass) ------
// rank[i] = (per-dst rank << 1) | unmasked_flag

__global__ void k_count(const int* __restrict__ dst, const float* __restrict__ elen,
                        int* __restrict__ ucnt, int* __restrict__ mcnt,
                        int* __restrict__ rank) {
  int i = blockIdx.x * blockDim.x + threadIdx.x;
  if (i < N_EDGES) {
    int d = dst[i];
    int m = (elen[i] <= CUTOFF) ? 1 : 0;
    int r = atomicAdd(m ? &ucnt[d] : &mcnt[d], 1);
    rank[i] = (r << 1) | m;
  }
}

// joint u+m local scan: blocks [0,NB) -> ucnt/urow, [NB,2NB) -> mcnt/mrow
__global__ __launch_bounds__(256) void k_scan_local(
    const int* __restrict__ ucnt, const int* __restrict__ mcnt,
    int* __restrict__ urow, int* __restrict__ mrow, int* __restrict__ bsum) {
  __shared__ int buf[256];
  int b = blockIdx.x, tid = threadIdx.x;
  const int* cnt = (b < NB_SCAN) ? ucnt : mcnt;
  int* row = (b < NB_SCAN) ? urow : mrow;
  int i = ((b < NB_SCAN) ? b : b - NB_SCAN) * 256 + tid;
  int v = (i < N_NODES) ? cnt[i] : 0;
  buf[tid] = v;
  __syncthreads();
  for (int off = 1; off < 256; off <<= 1) {
    int t = (tid >= off) ? buf[tid - off] : 0;
    __syncthreads();
    buf[tid] += t;
    __syncthreads();
  }
  if (i < N_NODES) row[i] = buf[tid] - v;  // local exclusive
  if (tid == 255) bsum[b] = buf[255];
}

// joint top scan over 2*NB block sums (m prefixes come out pre-offset by nUm)
__global__ __launch_bounds__(256) void k_scan_top(const int* __restrict__ bsum,
                                                  int* __restrict__ boff) {
  __shared__ int buf[256];
  int tid = threadIdx.x;
  int run = 0;
  for (int base = 0; base < 2 * NB_SCAN; base += 256) {
    int i = base + tid;
    int v = (i < 2 * NB_SCAN) ? bsum[i] : 0;
    buf[tid] = v;
    __syncthreads();
    for (int off = 1; off < 256; off <<= 1) {
      int t = (tid >= off) ? buf[tid - off] : 0;
      __syncthreads();
      buf[tid] += t;
      __syncthreads();
    }
    if (i < 2 * NB_SCAN) boff[i] = run + buf[tid] - v;
    run += buf[255];
    __syncthreads();
  }
  if (tid == 0) boff[2 * NB_SCAN] = run;  // = N_EDGES
}

// blocks [0, 2*NB): row += boff (+nUm for m side)
// blocks [2*NB, 2*NB+40): repack 5 weight mats into MFMA B-fragment order
// wp[mat*16384 + ((jt*4+kk)*64 + l)*8 + j]
//   = bf16( w[(kk*32 + (l>>4)*8 + j)*128 + jt*16 + (l&15)] )
__global__ __launch_bounds__(256) void k_scan_add_repack(
    int* __restrict__ urow, int* __restrict__ mrow, const int* __restrict__ boff,
    const float* __restrict__ w2a, const float* __restrict__ w2b,
    const float* __restrict__ w1a, const float* __restrict__ w1b,
    const float* __restrict__ w0b, __hip_bfloat16* __restrict__ wp) {
  int b = blockIdx.x, tid = threadIdx.x;
  if (b < 2 * NB_SCAN) {
    int* row = (b < NB_SCAN) ? urow : mrow;
    int i = ((b < NB_SCAN) ? b : b - NB_SCAN) * 256 + tid;
    if (i < N_NODES) row[i] += boff[b];
    if (tid == 0 && b == 0) urow[N_NODES] = boff[NB_SCAN];            // nUm
    if (tid == 0 && b == NB_SCAN) mrow[N_NODES] = boff[2 * NB_SCAN];  // N_EDGES
  } else {
    int gid = b - 2 * NB_SCAN;  // 0..39
    int mat = gid >> 3;
    const float* w = (mat == 0) ? w2a
                     : (mat == 1) ? w2b
                     : (mat == 2) ? w1a
                     : (mat == 3) ? w1b : w0b;
    int idx = (gid & 7) * 256 + tid;  // 0..2047 within mat
    int l = idx & 63;
    int f = idx >> 6;
    int kk = f & 3, jt = f >> 2;
    int col = jt * 16 + (l & 15);
    int kb = kk * 32 + (l >> 4) * 8;
    b16x8 o;
#pragma unroll
    for (int j = 0; j < 8; ++j) o.v[j] = __float2bfloat16(w[(kb + j) * HDIM + col]);
    *reinterpret_cast<b16x8*>(&wp[(size_t)mat * 16384 + idx * 8]) = o;
  }
}

// atomic-free scatter: slot = row[dst] + rank (mask decoded from rank low bit)
__global__ void k_scatter(const int* __restrict__ src, const int* __restrict__ dst,
                          const int* __restrict__ urow, const int* __restrict__ mrow,
                          const int* __restrict__ rank, int* __restrict__ esrc2,
                          int* __restrict__ uedge) {
  int i = blockIdx.x * blockDim.x + threadIdx.x;
  if (i < N_EDGES) {
    int d = dst[i];
    int rm = rank[i];
    int r = rm >> 1;
    if (rm & 1) {
      int p = urow[d] + r;
      esrc2[p] = src[i];
      if (p < WP_CAP) uedge[p] = i;
    } else {
      int q = mrow[d] + r;
      esrc2[q] = src[i];
    }
  }
}

#define SWZ(row, colByte) ((row) * 256 + ((colByte) ^ (((row) & 7) << 4)))

// ---------------- node embedding via MFMA: hb = bf16(relu(z@w0a+b0a)@w0b+b0b) ---
// Layer 1 (K=5) on VALU -> bf16 hidden in swizzled sA; layer 2 = MFMA.

__global__ __launch_bounds__(256) void k_node_emb_mfma(
    const float* __restrict__ z, const float* __restrict__ w0a,
    const float* __restrict__ b0a, const __hip_bfloat16* __restrict__ w0bP,
    const float* __restrict__ b0b, __hip_bfloat16* __restrict__ hb) {
  __shared__ char sA[64 * 256];  // 64 x 128 bf16, swizzled (hidden, then out)
  __shared__ float zs[64][NCH];
  __shared__ float w0as[NCH][HDIM];
  __shared__ float b0as[HDIM];
  const int tid = threadIdx.x;
  const int wv = tid >> 6, l = tid & 63;
  const int r0 = blockIdx.x * 64;

  for (int i = tid; i < NCH * HDIM; i += 256) w0as[i / HDIM][i % HDIM] = w0a[i];
  if (tid < HDIM) b0as[tid] = b0a[tid];
  for (int i = tid; i < 64 * NCH; i += 256) {
    int r = i / NCH, c = i % NCH;
    int gr = r0 + r;
    zs[r][c] = (gr < N_NODES) ? z[(size_t)gr * NCH + c] : 0.f;
  }

  // B-frags for layer 2 (independent global loads; hide under staging)
  bf8 B0[2][4];
#pragma unroll
  for (int nt = 0; nt < 2; ++nt)
#pragma unroll
    for (int kk = 0; kk < 4; ++kk) {
      int f = (2 * wv + nt) * 4 + kk;
      B0[nt][kk] = *reinterpret_cast<const bf8*>(&w0bP[(f * 64 + l) * 8]);
    }

  __syncthreads();

  // layer 1: hidden = relu(z@w0a + b0a) -> sA bf16 (1024 16B-chunks)
#pragma unroll
  for (int i = 0; i < 4; ++i) {
    int c = tid + i * 256;
    int row = c >> 4, col8 = (c & 15) * 8;
    float h8[8];
#pragma unroll
    for (int q = 0; q < 8; ++q) h8[q] = b0as[col8 + q];
#pragma unroll
    for (int c5 = 0; c5 < NCH; ++c5) {
      float zv = zs[row][c5];
#pragma unroll
      for (int q = 0; q < 8; ++q) h8[q] += zv * w0as[c5][col8 + q];
    }
    s8v o;
#pragma unroll
    for (int q = 0; q < 8; ++q) o[q] = f2bf(fmaxf(h8[q], 0.f));
    *reinterpret_cast<s8v*>(&sA[SWZ(row, col8 * 2)]) = o;
  }
  __syncthreads();

  // layer 2 via MFMA
  f32x4 acc[4][2];
  float bias[2];
#pragma unroll
  for (int nt = 0; nt < 2; ++nt) bias[nt] = b0b[(2 * wv + nt) * 16 + (l & 15)];
#pragma unroll
  for (int mt = 0; mt < 4; ++mt)
#pragma unroll
    for (int nt = 0; nt < 2; ++nt)
      acc[mt][nt] = (f32x4){bias[nt], bias[nt], bias[nt], bias[nt]};

#pragma unroll
  for (int kk = 0; kk < 4; ++kk)
#pragma unroll
    for (int mt = 0; mt < 4; ++mt) {
      int rowi = mt * 16 + (l & 15);
      int kByte = (kk * 32 + (l >> 4) * 8) * 2;
      bf8 a = *reinterpret_cast<const bf8*>(&sA[SWZ(rowi, kByte)]);
#pragma unroll
      for (int nt = 0; nt < 2; ++nt)
        acc[mt][nt] = __builtin_amdgcn_mfma_f32_16x16x32_bf16(a, B0[nt][kk],
                                                              acc[mt][nt], 0, 0, 0);
    }
  __syncthreads();  // all sA reads done

  // out -> sA bf16 (no relu, no residual)
#pragma unroll
  for (int mt = 0; mt < 4; ++mt)
#pragma unroll
    for (int nt = 0; nt < 2; ++nt) {
      int colb = ((2 * wv + nt) * 16 + (l & 15)) * 2;
#pragma unroll
      for (int i = 0; i < 4; ++i) {
        int rowi = mt * 16 + (l >> 4) * 4 + i;
        *reinterpret_cast<__hip_bfloat16*>(&sA[SWZ(rowi, colb)]) =
            __float2bfloat16(acc[mt][nt][i]);
      }
    }
  __syncthreads();

  // vector store -> hb
#pragma unroll
  for (int i = 0; i < 4; ++i) {
    int c = tid + i * 256;
    int row = c >> 4, col8 = (c & 15) * 8;
    int gr = r0 + row;
    if (gr < N_NODES) {
      s8v v = *reinterpret_cast<const s8v*>(&sA[SWZ(row, col8 * 2)]);
      *reinterpret_cast<s8v*>(&hb[(size_t)gr * HDIM + col8]) = v;
    }
  }
}

// ---------------- edge gate via MFMA, uCSR-slot order; single LDS tile ---------

__global__ __launch_bounds__(256) void k_edge_gate_mfma(
    const float* __restrict__ attr, const __hip_bfloat16* __restrict__ w2aP,
    const float* __restrict__ b2a, const __hip_bfloat16* __restrict__ w2bP,
    const float* __restrict__ b2b, const int* __restrict__ uedge,
    const int* __restrict__ nUmPtr, __hip_bfloat16* __restrict__ Wp) {
  __shared__ char sA[64 * 256];  // 64 x 128 bf16, swizzled (reused 3x)
  __shared__ int sEid[64];
  const int tid = threadIdx.x;
  const int wv = tid >> 6, l = tid & 63;
  const int e0 = blockIdx.x * 64;
  const int nUm = min(nUmPtr[0], WP_CAP);
  if (e0 >= nUm) return;

  if (tid < 64) {
    int idx = e0 + tid;
    sEid[tid] = uedge[(idx < nUm) ? idx : (nUm - 1)];
  }
  __syncthreads();

  // stage attr rows (gathered by edge id) -> sA bf16
#pragma unroll
  for (int i = 0; i < 8; ++i) {
    int c = tid + i * 256;
    int row = c >> 5, col4 = (c & 31) * 4;
    f4 v = *reinterpret_cast<const f4*>(&attr[(size_t)sEid[row] * HDIM + col4]);
    b16x4 o;
    o.v[0] = __float2bfloat16(v[0]);
    o.v[1] = __float2bfloat16(v[1]);
    o.v[2] = __float2bfloat16(v[2]);
    o.v[3] = __float2bfloat16(v[3]);
    *reinterpret_cast<b16x4*>(&sA[SWZ(row, col4 * 2)]) = o;
  }

  bf8 B1[2][4], B2[2][4];
#pragma unroll
  for (int nt = 0; nt < 2; ++nt)
#pragma unroll
    for (int kk = 0; kk < 4; ++kk) {
      int f = (2 * wv + nt) * 4 + kk;
      B1[nt][kk] = *reinterpret_cast<const bf8*>(&w2aP[(f * 64 + l) * 8]);
      B2[nt][kk] = *reinterpret_cast<const bf8*>(&w2bP[(f * 64 + l) * 8]);
    }

  __syncthreads();

  // layer 1
  f32x4 acc[4][2];
  float bias[2];
#pragma unroll
  for (int nt = 0; nt < 2; ++nt) bias[nt] = b2a[(2 * wv + nt) * 16 + (l & 15)];
#pragma unroll
  for (int mt = 0; mt < 4; ++mt)
#pragma unroll
    for (int nt = 0; nt < 2; ++nt)
      acc[mt][nt] = (f32x4){bias[nt], bias[nt], bias[nt], bias[nt]};

#pragma unroll
  for (int kk = 0; kk < 4; ++kk)
#pragma unroll
    for (int mt = 0; mt < 4; ++mt) {
      int row = mt * 16 + (l & 15);
      int kByte = (kk * 32 + (l >> 4) * 8) * 2;
      bf8 a = *reinterpret_cast<const bf8*>(&sA[SWZ(row, kByte)]);
#pragma unroll
      for (int nt = 0; nt < 2; ++nt)
        acc[mt][nt] = __builtin_amdgcn_mfma_f32_16x16x32_bf16(a, B1[nt][kk],
                                                              acc[mt][nt], 0, 0, 0);
    }
  __syncthreads();  // all sA reads done; safe to overwrite

  // hidden = relu(acc) -> sA
#pragma unroll
  for (int mt = 0; mt < 4; ++mt)
#pragma unroll
    for (int nt = 0; nt < 2; ++nt) {
      int colb = ((2 * wv + nt) * 16 + (l & 15)) * 2;
#pragma unroll
      for (int i = 0; i < 4; ++i) {
        int row = mt * 16 + (l >> 4) * 4 + i;
        *reinterpret_cast<__hip_bfloat16*>(&sA[SWZ(row, colb)]) =
            __float2bfloat16(fmaxf(acc[mt][nt][i], 0.f));
      }
    }
  __syncthreads();

  // layer 2
#pragma unroll
  for (int nt = 0; nt < 2; ++nt) bias[nt] = b2b[(2 * wv + nt) * 16 + (l & 15)];
#pragma unroll
  for (int mt = 0; mt < 4; ++mt)
#pragma unroll
    for (int nt = 0; nt < 2; ++nt)
      acc[mt][nt] = (f32x4){bias[nt], bias[nt], bias[nt], bias[nt]};

#pragma unroll
  for (int kk = 0; kk < 4; ++kk)
#pragma unroll
    for (int mt = 0; mt < 4; ++mt) {
      int row = mt * 16 + (l & 15);
      int kByte = (kk * 32 + (l >> 4) * 8) * 2;
      bf8 a = *reinterpret_cast<const bf8*>(&sA[SWZ(row, kByte)]);
#pragma unroll
      for (int nt = 0; nt < 2; ++nt)
        acc[mt][nt] = __builtin_amdgcn_mfma_f32_16x16x32_bf16(a, B2[nt][kk],
                                                              acc[mt][nt], 0, 0, 0);
    }
  __syncthreads();  // all layer-2 sA reads done

  // output -> sA
#pragma unroll
  for (int mt = 0; mt < 4; ++mt)
#pragma unroll
    for (int nt = 0; nt < 2; ++nt) {
      int colb = ((2 * wv + nt) * 16 + (l & 15)) * 2;
#pragma unroll
      for (int i = 0; i < 4; ++i) {
        int row = mt * 16 + (l >> 4) * 4 + i;
        *reinterpret_cast<__hip_bfloat16*>(&sA[SWZ(row, colb)]) =
            __float2bfloat16(acc[mt][nt][i]);
      }
    }
  __syncthreads();

  // contiguous store: Wp rows e0..e0+63, tail-guarded
#pragma unroll
  for (int i = 0; i < 4; ++i) {
    int c = tid + i * 256;
    int row = c >> 4, colc = c & 15;
    if (e0 + row < nUm) {
      b16x8 v = *reinterpret_cast<const b16x8*>(&sA[SWZ(row, colc * 16)]);
      *reinterpret_cast<b16x8*>(&Wp[(size_t)(e0 + row) * HDIM + colc * 8]) = v;
    }
  }
}

// ---------------- aggregate: sequential nodes, streamed Wp, bf16 out ------------
// agg_b[n] = bf16( sum_u relu(hb[src]+Wp[p]) + sum_m relu(hb[src]) )

__global__ __launch_bounds__(256) void k_aggregate(
    const __hip_bfloat16* __restrict__ hb, const __hip_bfloat16* __restrict__ Wp,
    const int* __restrict__ urow, const int* __restrict__ mrow,
    const int* __restrict__ esrc2, __hip_bfloat16* __restrict__ agg_b) {
  int tid = threadIdx.x;
  int node = blockIdx.x * 16 + (tid >> 4);
  if (node >= N_NODES) return;
  const int lane16 = tid & 15;
  const int grpBase = tid & 48;  // group's base lane within the 64-lane wave
  const int c8 = lane16 * 8;

  float s[8];
#pragma unroll
  for (int q = 0; q < 8; ++q) s[q] = 0.f;

  // ---- unmasked edges: hb gather + Wp stream
  int ub = urow[node], ueFull = urow[node + 1];
  int ue = min(ueFull, WP_CAP);
  for (int p0 = ub; p0 < ue; p0 += 16) {
    int cnt = ue - p0;
    if (cnt > 16) cnt = 16;
    int idx = (lane16 < cnt) ? esrc2[p0 + lane16] : 0;
    for (int j = 0; j < cnt; j += 4) {
      s8v hv[4], wv[4];
#pragma unroll
      for (int t = 0; t < 4; ++t) {
        int sr = __shfl(idx, grpBase + j + t, 64);
        if (j + t < cnt) {
          hv[t] = *reinterpret_cast<const s8v*>(&hb[(size_t)sr * HDIM + c8]);
          wv[t] = *reinterpret_cast<const s8v*>(&Wp[(size_t)(p0 + j + t) * HDIM + c8]);
        } else {
          hv[t] = (s8v)0;
          wv[t] = (s8v)0;
        }
      }
#pragma unroll
      for (int t = 0; t < 4; ++t)
#pragma unroll
        for (int q = 0; q < 8; ++q)
          s[q] += fmaxf(bf2f(hv[t][q]) + bf2f(wv[t][q]), 0.f);
    }
  }
  for (int p = ue; p < ueFull; ++p) {  // WP_CAP overflow guard (never in practice)
    int sr = esrc2[p];
    s8v hv = *reinterpret_cast<const s8v*>(&hb[(size_t)sr * HDIM + c8]);
#pragma unroll
    for (int q = 0; q < 8; ++q) s[q] += fmaxf(bf2f(hv[q]), 0.f);
  }

  // ---- masked edges: relu(hb) only
  int mb = mrow[node], me = mrow[node + 1];
  for (int p0 = mb; p0 < me; p0 += 16) {
    int cnt = me - p0;
    if (cnt > 16) cnt = 16;
    int idx = (lane16 < cnt) ? esrc2[p0 + lane16] : 0;
    for (int j = 0; j < cnt; j += 4) {
      s8v hv[4];
#pragma unroll
      for (int t = 0; t < 4; ++t) {
        int sr = __shfl(idx, grpBase + j + t, 64);
        if (j + t < cnt)
          hv[t] = *reinterpret_cast<const s8v*>(&hb[(size_t)sr * HDIM + c8]);
        else
          hv[t] = (s8v)0;
      }
#pragma unroll
      for (int t = 0; t < 4; ++t)
#pragma unroll
        for (int q = 0; q < 8; ++q) s[q] += fmaxf(bf2f(hv[t][q]), 0.f);
    }
  }

  s8v o;
#pragma unroll
  for (int q = 0; q < 8; ++q) o[q] = f2bf(s[q]);
  *reinterpret_cast<s8v*>(&agg_b[(size_t)node * HDIM + c8]) = o;
}

// ---------------- update via MFMA: hb += act(MLP1(agg + hb)); last -> f32 out ---
// Vectorized epilogue: act(out) routed through sA, hb re-read as 16B chunks.

__global__ __launch_bounds__(256) void k_update_mfma(
    const __hip_bfloat16* __restrict__ agg_b,
    const __hip_bfloat16* __restrict__ w1aP, const float* __restrict__ b1a,
    const __hip_bfloat16* __restrict__ w1bP, const float* __restrict__ b1b,
    __hip_bfloat16* __restrict__ hb, float* __restrict__ hout, int is_last) {
  __shared__ char sA[64 * 256];  // 64 x 128 bf16, swizzled (reused)
  const int tid = threadIdx.x;
  const int wv = tid >> 6, l = tid & 63;
  const int r0 = blockIdx.x * 64;

  // stage bf16(agg + hb) -> sA   (1024 16B-chunks)
#pragma unroll
  for (int i = 0; i < 4; ++i) {
    int c = tid + i * 256;
    int row = c >> 4, col8 = (c & 15) * 8;
    int gr = r0 + row;
    s8v o = (s8v)0;
    if (gr < N_NODES) {
      s8v a = *reinterpret_cast<const s8v*>(&agg_b[(size_t)gr * HDIM + col8]);
      s8v hh = *reinterpret_cast<const s8v*>(&hb[(size_t)gr * HDIM + col8]);
#pragma unroll
      for (int q = 0; q < 8; ++q) o[q] = f2bf(bf2f(a[q]) + bf2f(hh[q]));
    }
    *reinterpret_cast<s8v*>(&sA[SWZ(row, col8 * 2)]) = o;
  }

  bf8 B1[2][4], B2[2][4];
#pragma unroll
  for (int nt = 0; nt < 2; ++nt)
#pragma unroll
    for (int kk = 0; kk < 4; ++kk) {
      int f = (2 * wv + nt) * 4 + kk;
      B1[nt][kk] = *reinterpret_cast<const bf8*>(&w1aP[(f * 64 + l) * 8]);
      B2[nt][kk] = *reinterpret_cast<const bf8*>(&w1bP[(f * 64 + l) * 8]);
    }

  __syncthreads();

  // layer 1
  f32x4 acc[4][2];
  float bias[2];
#pragma unroll
  for (int nt = 0; nt < 2; ++nt) bias[nt] = b1a[(2 * wv + nt) * 16 + (l & 15)];
#pragma unroll
  for (int mt = 0; mt < 4; ++mt)
#pragma unroll
    for (int nt = 0; nt < 2; ++nt)
      acc[mt][nt] = (f32x4){bias[nt], bias[nt], bias[nt], bias[nt]};

#pragma unroll
  for (int kk = 0; kk < 4; ++kk)
#pragma unroll
    for (int mt = 0; mt < 4; ++mt) {
      int rowi = mt * 16 + (l & 15);
      int kByte = (kk * 32 + (l >> 4) * 8) * 2;
      bf8 a = *reinterpret_cast<const bf8*>(&sA[SWZ(rowi, kByte)]);
#pragma unroll
      for (int nt = 0; nt < 2; ++nt)
        acc[mt][nt] = __builtin_amdgcn_mfma_f32_16x16x32_bf16(a, B1[nt][kk],
                                                              acc[mt][nt], 0, 0, 0);
    }
  __syncthreads();  // all sA reads done

  // hidden -> sA
#pragma unroll
  for (int mt = 0; mt < 4; ++mt)
#pragma unroll
    for (int nt = 0; nt < 2; ++nt) {
      int colb = ((2 * wv + nt) * 16 + (l & 15)) * 2;
#pragma unroll
      for (int i = 0; i < 4; ++i) {
        int rowi = mt * 16 + (l >> 4) * 4 + i;
        *reinterpret_cast<__hip_bfloat16*>(&sA[SWZ(rowi, colb)]) =
            __float2bfloat16(fmaxf(acc[mt][nt][i], 0.f));
      }
    }
  __syncthreads();

  // layer 2
#pragma unroll
  for (int nt = 0; nt < 2; ++nt) bias[nt] = b1b[(2 * wv + nt) * 16 + (l & 15)];
#pragma unroll
  for (int mt = 0; mt < 4; ++mt)
#pragma unroll
    for (int nt = 0; nt < 2; ++nt)
      acc[mt][nt] = (f32x4){bias[nt], bias[nt], bias[nt], bias[nt]};

#pragma unroll
  for (int kk = 0; kk < 4; ++kk)
#pragma unroll
    for (int mt = 0; mt < 4; ++mt) {
      int rowi = mt * 16 + (l & 15);
      int kByte = (kk * 32 + (l >> 4) * 8) * 2;
      bf8 a = *reinterpret_cast<const bf8*>(&sA[SWZ(rowi, kByte)]);
#pragma unroll
      for (int nt = 0; nt < 2; ++nt)
        acc[mt][nt] = __builtin_amdgcn_mfma_f32_16x16x32_bf16(a, B2[nt][kk],
                                                              acc[mt][nt], 0, 0, 0);
    }
  __syncthreads();  // all layer-2 sA reads done

  // act(out) -> sA (bf16); last conv keeps raw (no relu)
#pragma unroll
  for (int mt = 0; mt < 4; ++mt)
#pragma unroll
    for (int nt = 0; nt < 2; ++nt) {
      int colb = ((2 * wv + nt) * 16 + (l & 15)) * 2;
#pragma unroll
      for (int i = 0; i < 4; ++i) {
        int rowi = mt * 16 + (l >> 4) * 4 + i;
        float t = acc[mt][nt][i];
        if (!is_last) t = fmaxf(t, 0.f);
        *reinterpret_cast<__hip_bfloat16*>(&sA[SWZ(rowi, colb)]) =
            __float2bfloat16(t);
      }
    }
  __syncthreads();

  // vector epilogue: nh = hb + t; last conv -> f32 d_out, else -> hb
#pragma unroll
  for (int i = 0; i < 4; ++i) {
    int c = tid + i * 256;
    int row = c >> 4, col8 = (c & 15) * 8;
    int gr = r0 + row;
    if (gr < N_NODES) {
      s8v tv = *reinterpret_cast<const s8v*>(&sA[SWZ(row, col8 * 2)]);
      s8v hh = *reinterpret_cast<const s8v*>(&hb[(size_t)gr * HDIM + col8]);
      if (is_last) {
        f4 o0, o1;
#pragma unroll
        for (int q = 0; q < 4; ++q) o0[q] = bf2f(hh[q]) + bf2f(tv[q]);
#pragma unroll
        for (int q = 0; q < 4; ++q) o1[q] = bf2f(hh[q + 4]) + bf2f(tv[q + 4]);
        *reinterpret_cast<f4*>(&hout[(size_t)gr * HDIM + col8]) = o0;
        *reinterpret_cast<f4*>(&hout[(size_t)gr * HDIM + col8 + 4]) = o1;
      } else {
        s8v o;
#pragma unroll
        for (int q = 0; q < 8; ++q) o[q] = f2bf(bf2f(hh[q]) + bf2f(tv[q]));
        *reinterpret_cast<s8v*>(&hb[(size_t)gr * HDIM + col8]) = o;
      }
    }
  }
}

// ---------------- launch --------------------------------------------------------

extern "C" void kernel_launch(void* const* d_in, const int* in_sizes, int n_in,
                              void* d_out, int out_size, void* d_ws, size_t ws_size,
                              hipStream_t stream) {
  const float* z = (const float*)d_in[0];
  const int* ei = (const int*)d_in[1];
  const float* attr = (const float*)d_in[2];
  const float* elen = (const float*)d_in[3];
  const float* w0a = (const float*)d_in[4];
  const float* b0a = (const float*)d_in[5];
  const float* w0b = (const float*)d_in[6];
  const float* b0b = (const float*)d_in[7];
  const float* w1a = (const float*)d_in[8];
  const float* b1a = (const float*)d_in[9];
  const float* w1b = (const float*)d_in[10];
  const float* b1b = (const float*)d_in[11];
  const float* w2a = (const float*)d_in[12];
  const float* b2a = (const float*)d_in[13];
  const float* w2b = (const float*)d_in[14];
  const float* b2b = (const float*)d_in[15];

  float* hout = (float*)d_out;

  char* ws = (char*)d_ws;
  size_t off = 0;
  __hip_bfloat16* Wp = (__hip_bfloat16*)(ws + off);
  off += (size_t)WP_CAP * HDIM * 2;           // 184.3 MB
  __hip_bfloat16* agg_b = (__hip_bfloat16*)(ws + off);
  off += (size_t)N_NODES * HDIM * 2;          // 12.8 MB
  __hip_bfloat16* hb = (__hip_bfloat16*)(ws + off);
  off += (size_t)N_NODES * HDIM * 2;          // 12.8 MB
  int* esrc2 = (int*)(ws + off);
  off += (size_t)N_EDGES * 4;                 // 3.2 MB
  int* uedge = (int*)(ws + off);
  off += (size_t)WP_CAP * 4;                  // 2.88 MB
  int* rank = (int*)(ws + off);
  off += (size_t)N_EDGES * 4;                 // 3.2 MB
  int* urow = (int*)(ws + off);
  off += (size_t)(N_NODES + 64) * 4;
  int* mrow = (int*)(ws + off);
  off += (size_t)(N_NODES + 64) * 4;
  // zero-init region: [ucnt][mcnt] — one memset
  int* ucnt = (int*)(ws + off);
  off += (size_t)N_NODES * 4;
  int* mcnt = (int*)(ws + off);
  off += (size_t)N_NODES * 4;
  int* bsum = (int*)(ws + off);
  off += (size_t)(2 * NB_SCAN + 8) * 4;
  int* boff = (int*)(ws + off);
  off += (size_t)(2 * NB_SCAN + 8) * 4;
  __hip_bfloat16* wPk = (__hip_bfloat16*)(ws + off);  // [w2a|w2b|w1a|w1b|w0b]
  off += (size_t)5 * HDIM * HDIM * 2;                 // 160 KB
  __hip_bfloat16* w2aP = wPk;
  __hip_bfloat16* w2bP = wPk + 16384;
  __hip_bfloat16* w1aP = wPk + 2 * 16384;
  __hip_bfloat16* w1bP = wPk + 3 * 16384;
  __hip_bfloat16* w0bP = wPk + 4 * 16384;

  const int* src = ei;
  const int* dst = ei + N_EDGES;

  // split CSR build (single atomic pass; mask packed into rank)
  hipMemsetAsync(ucnt, 0, (size_t)(2 * N_NODES) * 4, stream);
  k_count<<<(N_EDGES + 255) / 256, 256, 0, stream>>>(dst, elen, ucnt, mcnt, rank);
  k_scan_local<<<2 * NB_SCAN, 256, 0, stream>>>(ucnt, mcnt, urow, mrow, bsum);
  k_scan_top<<<1, 256, 0, stream>>>(bsum, boff);
  k_scan_add_repack<<<2 * NB_SCAN + 40, 256, 0, stream>>>(
      urow, mrow, boff, w2a, w2b, w1a, w1b, w0b, wPk);
  k_scatter<<<(N_EDGES + 255) / 256, 256, 0, stream>>>(src, dst, urow, mrow, rank,
                                                       esrc2, uedge);

  // node embedding (layer1 VALU + layer2 MFMA) -> hb
  k_node_emb_mfma<<<(N_NODES + 63) / 64, 256, 0, stream>>>(z, w0a, b0a, w0bP, b0b,
                                                           hb);

  // edge gate in uCSR-slot order (worst-case grid; blocks past nUm exit early)
  k_edge_gate_mfma<<<(N_EDGES + 63) / 64, 256, 0, stream>>>(
      attr, w2aP, b2a, w2bP, b2b, uedge, &urow[N_NODES], Wp);

  // convs (bf16 hb master; final conv writes f32 d_out)
  for (int conv = 0; conv < 3; ++conv) {
    k_aggregate<<<(N_NODES + 15) / 16, 256, 0, stream>>>(hb, Wp, urow, mrow, esrc2,
                                                         agg_b);
    k_update_mfma<<<(N_NODES + 63) / 64, 256, 0, stream>>>(
        agg_b, w1aP, b1a, w1bP, b1b, hb, hout, conv == 2 ? 1 : 0);
  }
}

// Round 12
// 349.690 us; speedup vs baseline: 1.1421x; 1.0120x over previous
//
#include <hip/hip_runtime.h>
#include <hip/hip_bf16.h>

#define N_NODES 50000
#define N_EDGES 800000
#define HDIM 128
#define NCH 5
#define NB_SCAN ((N_NODES + 255) / 256)  // 196
#define NB_EMB ((N_NODES + 63) / 64)     // 782
#define CUTOFF 10.0f
#define WP_CAP 720000  // Wp row capacity; expected ~400k unmasked (guarded)

typedef float f4 __attribute__((ext_vector_type(4)));
typedef short bf8 __attribute__((ext_vector_type(8)));    // 8 bf16 = MFMA A/B frag
typedef short s8v __attribute__((ext_vector_type(8)));    // raw 8x bf16 bits
typedef float f32x4 __attribute__((ext_vector_type(4)));  // MFMA C/D frag

struct __align__(8) b16x4 { __hip_bfloat16 v[4]; };
struct __align__(16) b16x8 { __hip_bfloat16 v[8]; };

__device__ __forceinline__ float bf2f(short u) {
  return __uint_as_float(((unsigned)(unsigned short)u) << 16);
}
__device__ __forceinline__ short f2bf(float f) {
  return (short)__bfloat16_as_ushort(__float2bfloat16(f));
}

// ---------------- CSR build (split: unmasked / masked; single atomic pass) ------
// rank[i] = (per-dst rank << 1) | unmasked_flag

__global__ void k_count(const int* __restrict__ dst, const float* __restrict__ elen,
                        int* __restrict__ ucnt, int* __restrict__ mcnt,
                        int* __restrict__ rank) {
  int i = blockIdx.x * blockDim.x + threadIdx.x;
  if (i < N_EDGES) {
    int d = dst[i];
    int m = (elen[i] <= CUTOFF) ? 1 : 0;
    int r = atomicAdd(m ? &ucnt[d] : &mcnt[d], 1);
    rank[i] = (r << 1) | m;
  }
}

// joint u+m local scan: blocks [0,NB) -> ucnt/urow, [NB,2NB) -> mcnt/mrow
__global__ __launch_bounds__(256) void k_scan_local(
    const int* __restrict__ ucnt, const int* __restrict__ mcnt,
    int* __restrict__ urow, int* __restrict__ mrow, int* __restrict__ bsum) {
  __shared__ int buf[256];
  int b = blockIdx.x, tid = threadIdx.x;
  const int* cnt = (b < NB_SCAN) ? ucnt : mcnt;
  int* row = (b < NB_SCAN) ? urow : mrow;
  int i = ((b < NB_SCAN) ? b : b - NB_SCAN) * 256 + tid;
  int v = (i < N_NODES) ? cnt[i] : 0;
  buf[tid] = v;
  __syncthreads();
  for (int off = 1; off < 256; off <<= 1) {
    int t = (tid >= off) ? buf[tid - off] : 0;
    __syncthreads();
    buf[tid] += t;
    __syncthreads();
  }
  if (i < N_NODES) row[i] = buf[tid] - v;  // local exclusive
  if (tid == 255) bsum[b] = buf[255];
}

// joint top scan over 2*NB block sums (m prefixes come out pre-offset by nUm)
__global__ __launch_bounds__(256) void k_scan_top(const int* __restrict__ bsum,
                                                  int* __restrict__ boff) {
  __shared__ int buf[256];
  int tid = threadIdx.x;
  int run = 0;
  for (int base = 0; base < 2 * NB_SCAN; base += 256) {
    int i = base + tid;
    int v = (i < 2 * NB_SCAN) ? bsum[i] : 0;
    buf[tid] = v;
    __syncthreads();
    for (int off = 1; off < 256; off <<= 1) {
      int t = (tid >= off) ? buf[tid - off] : 0;
      __syncthreads();
      buf[tid] += t;
      __syncthreads();
    }
    if (i < 2 * NB_SCAN) boff[i] = run + buf[tid] - v;
    run += buf[255];
    __syncthreads();
  }
  if (tid == 0) boff[2 * NB_SCAN] = run;  // = N_EDGES
}

// blocks [0, 2*NB): row += boff (+nUm for m side)
// blocks [2*NB, 2*NB+40): repack 5 weight mats into MFMA B-fragment order
// wp[mat*16384 + ((jt*4+kk)*64 + l)*8 + j]
//   = bf16( w[(kk*32 + (l>>4)*8 + j)*128 + jt*16 + (l&15)] )
__global__ __launch_bounds__(256) void k_scan_add_repack(
    int* __restrict__ urow, int* __restrict__ mrow, const int* __restrict__ boff,
    const float* __restrict__ w2a, const float* __restrict__ w2b,
    const float* __restrict__ w1a, const float* __restrict__ w1b,
    const float* __restrict__ w0b, __hip_bfloat16* __restrict__ wp) {
  int b = blockIdx.x, tid = threadIdx.x;
  if (b < 2 * NB_SCAN) {
    int* row = (b < NB_SCAN) ? urow : mrow;
    int i = ((b < NB_SCAN) ? b : b - NB_SCAN) * 256 + tid;
    if (i < N_NODES) row[i] += boff[b];
    if (tid == 0 && b == 0) urow[N_NODES] = boff[NB_SCAN];            // nUm
    if (tid == 0 && b == NB_SCAN) mrow[N_NODES] = boff[2 * NB_SCAN];  // N_EDGES
  } else {
    int gid = b - 2 * NB_SCAN;  // 0..39
    int mat = gid >> 3;
    const float* w = (mat == 0) ? w2a
                     : (mat == 1) ? w2b
                     : (mat == 2) ? w1a
                     : (mat == 3) ? w1b : w0b;
    int idx = (gid & 7) * 256 + tid;  // 0..2047 within mat
    int l = idx & 63;
    int f = idx >> 6;
    int kk = f & 3, jt = f >> 2;
    int col = jt * 16 + (l & 15);
    int kb = kk * 32 + (l >> 4) * 8;
    b16x8 o;
#pragma unroll
    for (int j = 0; j < 8; ++j) o.v[j] = __float2bfloat16(w[(kb + j) * HDIM + col]);
    *reinterpret_cast<b16x8*>(&wp[(size_t)mat * 16384 + idx * 8]) = o;
  }
}

// atomic-free scatter: slot = row[dst] + rank (mask decoded from rank low bit)
__global__ void k_scatter(const int* __restrict__ src, const int* __restrict__ dst,
                          const int* __restrict__ urow, const int* __restrict__ mrow,
                          const int* __restrict__ rank, int* __restrict__ esrc2,
                          int* __restrict__ uedge) {
  int i = blockIdx.x * blockDim.x + threadIdx.x;
  if (i < N_EDGES) {
    int d = dst[i];
    int rm = rank[i];
    int r = rm >> 1;
    if (rm & 1) {
      int p = urow[d] + r;
      esrc2[p] = src[i];
      if (p < WP_CAP) uedge[p] = i;
    } else {
      int q = mrow[d] + r;
      esrc2[q] = src[i];
    }
  }
}

#define SWZ(row, colByte) ((row) * 256 + ((colByte) ^ (((row) & 7) << 4)))

// ---------------- fused node-embedding + edge-gate dispatch ---------------------
// blocks [0, NB_EMB): hb = bf16(relu(z@w0a+b0a)@w0b + b0b)   (layer2 via MFMA)
// blocks [NB_EMB, ..): edge gate MLP over uCSR-slot order -> Wp

__global__ __launch_bounds__(256) void k_emb_gate_mfma(
    const float* __restrict__ z, const float* __restrict__ w0a,
    const float* __restrict__ b0a, const __hip_bfloat16* __restrict__ w0bP,
    const float* __restrict__ b0b, __hip_bfloat16* __restrict__ hb,
    const float* __restrict__ attr, const __hip_bfloat16* __restrict__ w2aP,
    const float* __restrict__ b2a, const __hip_bfloat16* __restrict__ w2bP,
    const float* __restrict__ b2b, const int* __restrict__ uedge,
    const int* __restrict__ nUmPtr, __hip_bfloat16* __restrict__ Wp) {
  __shared__ char sA[64 * 256];  // 64 x 128 bf16, swizzled (multi-purpose)
  __shared__ char sx[4352];      // overlay: emb {zs|w0as|b0as} / gate {sEid}
  const int tid = threadIdx.x;
  const int wv = tid >> 6, l = tid & 63;

  if (blockIdx.x < NB_EMB) {
    // ================= node embedding =================
    float (*zs)[NCH] = (float(*)[NCH])sx;              // 64*5*4   = 1280 B
    float (*w0as)[HDIM] = (float(*)[HDIM])(sx + 1280); // 5*128*4  = 2560 B
    float* b0as = (float*)(sx + 1280 + 2560);          // 128*4    = 512 B
    const int r0 = blockIdx.x * 64;

    for (int i = tid; i < NCH * HDIM; i += 256) w0as[i / HDIM][i % HDIM] = w0a[i];
    if (tid < HDIM) b0as[tid] = b0a[tid];
    for (int i = tid; i < 64 * NCH; i += 256) {
      int r = i / NCH, c = i % NCH;
      int gr = r0 + r;
      zs[r][c] = (gr < N_NODES) ? z[(size_t)gr * NCH + c] : 0.f;
    }

    bf8 B0[2][4];
#pragma unroll
    for (int nt = 0; nt < 2; ++nt)
#pragma unroll
      for (int kk = 0; kk < 4; ++kk) {
        int f = (2 * wv + nt) * 4 + kk;
        B0[nt][kk] = *reinterpret_cast<const bf8*>(&w0bP[(f * 64 + l) * 8]);
      }

    __syncthreads();

    // layer 1: hidden = relu(z@w0a + b0a) -> sA bf16
#pragma unroll
    for (int i = 0; i < 4; ++i) {
      int c = tid + i * 256;
      int row = c >> 4, col8 = (c & 15) * 8;
      float h8[8];
#pragma unroll
      for (int q = 0; q < 8; ++q) h8[q] = b0as[col8 + q];
#pragma unroll
      for (int c5 = 0; c5 < NCH; ++c5) {
        float zv = zs[row][c5];
#pragma unroll
        for (int q = 0; q < 8; ++q) h8[q] += zv * w0as[c5][col8 + q];
      }
      s8v o;
#pragma unroll
      for (int q = 0; q < 8; ++q) o[q] = f2bf(fmaxf(h8[q], 0.f));
      *reinterpret_cast<s8v*>(&sA[SWZ(row, col8 * 2)]) = o;
    }
    __syncthreads();

    // layer 2 via MFMA
    f32x4 acc[4][2];
    float bias[2];
#pragma unroll
    for (int nt = 0; nt < 2; ++nt) bias[nt] = b0b[(2 * wv + nt) * 16 + (l & 15)];
#pragma unroll
    for (int mt = 0; mt < 4; ++mt)
#pragma unroll
      for (int nt = 0; nt < 2; ++nt)
        acc[mt][nt] = (f32x4){bias[nt], bias[nt], bias[nt], bias[nt]};

#pragma unroll
    for (int kk = 0; kk < 4; ++kk)
#pragma unroll
      for (int mt = 0; mt < 4; ++mt) {
        int rowi = mt * 16 + (l & 15);
        int kByte = (kk * 32 + (l >> 4) * 8) * 2;
        bf8 a = *reinterpret_cast<const bf8*>(&sA[SWZ(rowi, kByte)]);
#pragma unroll
        for (int nt = 0; nt < 2; ++nt)
          acc[mt][nt] = __builtin_amdgcn_mfma_f32_16x16x32_bf16(a, B0[nt][kk],
                                                                acc[mt][nt], 0, 0, 0);
      }
    __syncthreads();

    // out -> sA bf16
#pragma unroll
    for (int mt = 0; mt < 4; ++mt)
#pragma unroll
      for (int nt = 0; nt < 2; ++nt) {
        int colb = ((2 * wv + nt) * 16 + (l & 15)) * 2;
#pragma unroll
        for (int i = 0; i < 4; ++i) {
          int rowi = mt * 16 + (l >> 4) * 4 + i;
          *reinterpret_cast<__hip_bfloat16*>(&sA[SWZ(rowi, colb)]) =
              __float2bfloat16(acc[mt][nt][i]);
        }
      }
    __syncthreads();

    // vector store -> hb
#pragma unroll
    for (int i = 0; i < 4; ++i) {
      int c = tid + i * 256;
      int row = c >> 4, col8 = (c & 15) * 8;
      int gr = r0 + row;
      if (gr < N_NODES) {
        s8v v = *reinterpret_cast<const s8v*>(&sA[SWZ(row, col8 * 2)]);
        *reinterpret_cast<s8v*>(&hb[(size_t)gr * HDIM + col8]) = v;
      }
    }
    return;
  }

  // ================= edge gate =================
  int* sEid = (int*)sx;
  const int e0 = (blockIdx.x - NB_EMB) * 64;
  const int nUm = min(nUmPtr[0], WP_CAP);
  if (e0 >= nUm) return;

  if (tid < 64) {
    int idx = e0 + tid;
    sEid[tid] = uedge[(idx < nUm) ? idx : (nUm - 1)];
  }
  __syncthreads();

  // stage attr rows (gathered by edge id) -> sA bf16
#pragma unroll
  for (int i = 0; i < 8; ++i) {
    int c = tid + i * 256;
    int row = c >> 5, col4 = (c & 31) * 4;
    f4 v = *reinterpret_cast<const f4*>(&attr[(size_t)sEid[row] * HDIM + col4]);
    b16x4 o;
    o.v[0] = __float2bfloat16(v[0]);
    o.v[1] = __float2bfloat16(v[1]);
    o.v[2] = __float2bfloat16(v[2]);
    o.v[3] = __float2bfloat16(v[3]);
    *reinterpret_cast<b16x4*>(&sA[SWZ(row, col4 * 2)]) = o;
  }

  bf8 B1[2][4], B2[2][4];
#pragma unroll
  for (int nt = 0; nt < 2; ++nt)
#pragma unroll
    for (int kk = 0; kk < 4; ++kk) {
      int f = (2 * wv + nt) * 4 + kk;
      B1[nt][kk] = *reinterpret_cast<const bf8*>(&w2aP[(f * 64 + l) * 8]);
      B2[nt][kk] = *reinterpret_cast<const bf8*>(&w2bP[(f * 64 + l) * 8]);
    }

  __syncthreads();

  // layer 1
  f32x4 acc[4][2];
  float bias[2];
#pragma unroll
  for (int nt = 0; nt < 2; ++nt) bias[nt] = b2a[(2 * wv + nt) * 16 + (l & 15)];
#pragma unroll
  for (int mt = 0; mt < 4; ++mt)
#pragma unroll
    for (int nt = 0; nt < 2; ++nt)
      acc[mt][nt] = (f32x4){bias[nt], bias[nt], bias[nt], bias[nt]};

#pragma unroll
  for (int kk = 0; kk < 4; ++kk)
#pragma unroll
    for (int mt = 0; mt < 4; ++mt) {
      int row = mt * 16 + (l & 15);
      int kByte = (kk * 32 + (l >> 4) * 8) * 2;
      bf8 a = *reinterpret_cast<const bf8*>(&sA[SWZ(row, kByte)]);
#pragma unroll
      for (int nt = 0; nt < 2; ++nt)
        acc[mt][nt] = __builtin_amdgcn_mfma_f32_16x16x32_bf16(a, B1[nt][kk],
                                                              acc[mt][nt], 0, 0, 0);
    }
  __syncthreads();  // all sA reads done; safe to overwrite

  // hidden = relu(acc) -> sA
#pragma unroll
  for (int mt = 0; mt < 4; ++mt)
#pragma unroll
    for (int nt = 0; nt < 2; ++nt) {
      int colb = ((2 * wv + nt) * 16 + (l & 15)) * 2;
#pragma unroll
      for (int i = 0; i < 4; ++i) {
        int row = mt * 16 + (l >> 4) * 4 + i;
        *reinterpret_cast<__hip_bfloat16*>(&sA[SWZ(row, colb)]) =
            __float2bfloat16(fmaxf(acc[mt][nt][i], 0.f));
      }
    }
  __syncthreads();

  // layer 2
#pragma unroll
  for (int nt = 0; nt < 2; ++nt) bias[nt] = b2b[(2 * wv + nt) * 16 + (l & 15)];
#pragma unroll
  for (int mt = 0; mt < 4; ++mt)
#pragma unroll
    for (int nt = 0; nt < 2; ++nt)
      acc[mt][nt] = (f32x4){bias[nt], bias[nt], bias[nt], bias[nt]};

#pragma unroll
  for (int kk = 0; kk < 4; ++kk)
#pragma unroll
    for (int mt = 0; mt < 4; ++mt) {
      int row = mt * 16 + (l & 15);
      int kByte = (kk * 32 + (l >> 4) * 8) * 2;
      bf8 a = *reinterpret_cast<const bf8*>(&sA[SWZ(row, kByte)]);
#pragma unroll
      for (int nt = 0; nt < 2; ++nt)
        acc[mt][nt] = __builtin_amdgcn_mfma_f32_16x16x32_bf16(a, B2[nt][kk],
                                                              acc[mt][nt], 0, 0, 0);
    }
  __syncthreads();  // all layer-2 sA reads done

  // output -> sA
#pragma unroll
  for (int mt = 0; mt < 4; ++mt)
#pragma unroll
    for (int nt = 0; nt < 2; ++nt) {
      int colb = ((2 * wv + nt) * 16 + (l & 15)) * 2;
#pragma unroll
      for (int i = 0; i < 4; ++i) {
        int row = mt * 16 + (l >> 4) * 4 + i;
        *reinterpret_cast<__hip_bfloat16*>(&sA[SWZ(row, colb)]) =
            __float2bfloat16(acc[mt][nt][i]);
      }
    }
  __syncthreads();

  // contiguous store: Wp rows e0..e0+63, tail-guarded
#pragma unroll
  for (int i = 0; i < 4; ++i) {
    int c = tid + i * 256;
    int row = c >> 4, colc = c & 15;
    if (e0 + row < nUm) {
      b16x8 v = *reinterpret_cast<const b16x8*>(&sA[SWZ(row, colc * 16)]);
      *reinterpret_cast<b16x8*>(&Wp[(size_t)(e0 + row) * HDIM + colc * 8]) = v;
    }
  }
}

// ---------------- aggregate batch helpers (order-preserving) --------------------

__device__ __forceinline__ void agg_batch_u(
    const __hip_bfloat16* __restrict__ hb, const __hip_bfloat16* __restrict__ Wp,
    int idx, int p0, int cnt, int grpBase, int c8, float s[8]) {
  for (int j = 0; j < cnt; j += 4) {
    s8v hv[4], wv[4];
#pragma unroll
    for (int t = 0; t < 4; ++t) {
      int sr = __shfl(idx, grpBase + j + t, 64);
      if (j + t < cnt) {
        hv[t] = *reinterpret_cast<const s8v*>(&hb[(size_t)sr * HDIM + c8]);
        wv[t] = *reinterpret_cast<const s8v*>(&Wp[(size_t)(p0 + j + t) * HDIM + c8]);
      } else {
        hv[t] = (s8v)0;
        wv[t] = (s8v)0;
      }
    }
#pragma unroll
    for (int t = 0; t < 4; ++t)
#pragma unroll
      for (int q = 0; q < 8; ++q)
        s[q] += fmaxf(bf2f(hv[t][q]) + bf2f(wv[t][q]), 0.f);
  }
}

__device__ __forceinline__ void agg_batch_m(
    const __hip_bfloat16* __restrict__ hb, int idx, int cnt, int grpBase, int c8,
    float s[8]) {
  for (int j = 0; j < cnt; j += 4) {
    s8v hv[4];
#pragma unroll
    for (int t = 0; t < 4; ++t) {
      int sr = __shfl(idx, grpBase + j + t, 64);
      if (j + t < cnt)
        hv[t] = *reinterpret_cast<const s8v*>(&hb[(size_t)sr * HDIM + c8]);
      else
        hv[t] = (s8v)0;
    }
#pragma unroll
    for (int t = 0; t < 4; ++t)
#pragma unroll
      for (int q = 0; q < 8; ++q) s[q] += fmaxf(bf2f(hv[t][q]), 0.f);
  }
}

// ---------------- aggregate: dual-chain prefetch (u + m idx loads overlap) ------
// agg_b[n] = bf16( sum_u relu(hb[src]+Wp[p]) + sum_m relu(hb[src]) )

__global__ __launch_bounds__(256) void k_aggregate(
    const __hip_bfloat16* __restrict__ hb, const __hip_bfloat16* __restrict__ Wp,
    const int* __restrict__ urow, const int* __restrict__ mrow,
    const int* __restrict__ esrc2, __hip_bfloat16* __restrict__ agg_b) {
  int tid = threadIdx.x;
  int node = blockIdx.x * 16 + (tid >> 4);
  if (node >= N_NODES) return;
  const int lane16 = tid & 15;
  const int grpBase = tid & 48;  // group's base lane within the 64-lane wave
  const int c8 = lane16 * 8;

  int ub = urow[node], ueFull = urow[node + 1];
  int ue = min(ueFull, WP_CAP);
  int mb = mrow[node], me = mrow[node + 1];
  int cntU0 = min(ue - ub, 16);
  int cntM0 = min(me - mb, 16);
  // both first-batch index loads issued before any gather (chains overlap)
  int idxU = (lane16 < cntU0) ? esrc2[ub + lane16] : 0;
  int idxM = (lane16 < cntM0) ? esrc2[mb + lane16] : 0;

  float s[8];
#pragma unroll
  for (int q = 0; q < 8; ++q) s[q] = 0.f;

  // ---- unmasked edges: hb gather + Wp stream
  if (cntU0 > 0) agg_batch_u(hb, Wp, idxU, ub, cntU0, grpBase, c8, s);
  for (int p0 = ub + 16; p0 < ue; p0 += 16) {
    int cnt = min(ue - p0, 16);
    int idx = (lane16 < cnt) ? esrc2[p0 + lane16] : 0;
    agg_batch_u(hb, Wp, idx, p0, cnt, grpBase, c8, s);
  }
  for (int p = ue; p < ueFull; ++p) {  // WP_CAP overflow guard (never in practice)
    int sr = esrc2[p];
    s8v hv = *reinterpret_cast<const s8v*>(&hb[(size_t)sr * HDIM + c8]);
#pragma unroll
    for (int q = 0; q < 8; ++q) s[q] += fmaxf(bf2f(hv[q]), 0.f);
  }

  // ---- masked edges: relu(hb) only
  if (cntM0 > 0) agg_batch_m(hb, idxM, cntM0, grpBase, c8, s);
  for (int p0 = mb + 16; p0 < me; p0 += 16) {
    int cnt = min(me - p0, 16);
    int idx = (lane16 < cnt) ? esrc2[p0 + lane16] : 0;
    agg_batch_m(hb, idx, cnt, grpBase, c8, s);
  }

  s8v o;
#pragma unroll
  for (int q = 0; q < 8; ++q) o[q] = f2bf(s[q]);
  *reinterpret_cast<s8v*>(&agg_b[(size_t)node * HDIM + c8]) = o;
}

// ---------------- update via MFMA: hb += act(MLP1(agg + hb)); last -> f32 out ---
// Vectorized epilogue: act(out) routed through sA, hb re-read as 16B chunks.

__global__ __launch_bounds__(256) void k_update_mfma(
    const __hip_bfloat16* __restrict__ agg_b,
    const __hip_bfloat16* __restrict__ w1aP, const float* __restrict__ b1a,
    const __hip_bfloat16* __restrict__ w1bP, const float* __restrict__ b1b,
    __hip_bfloat16* __restrict__ hb, float* __restrict__ hout, int is_last) {
  __shared__ char sA[64 * 256];  // 64 x 128 bf16, swizzled (reused)
  const int tid = threadIdx.x;
  const int wv = tid >> 6, l = tid & 63;
  const int r0 = blockIdx.x * 64;

  // stage bf16(agg + hb) -> sA   (1024 16B-chunks)
#pragma unroll
  for (int i = 0; i < 4; ++i) {
    int c = tid + i * 256;
    int row = c >> 4, col8 = (c & 15) * 8;
    int gr = r0 + row;
    s8v o = (s8v)0;
    if (gr < N_NODES) {
      s8v a = *reinterpret_cast<const s8v*>(&agg_b[(size_t)gr * HDIM + col8]);
      s8v hh = *reinterpret_cast<const s8v*>(&hb[(size_t)gr * HDIM + col8]);
#pragma unroll
      for (int q = 0; q < 8; ++q) o[q] = f2bf(bf2f(a[q]) + bf2f(hh[q]));
    }
    *reinterpret_cast<s8v*>(&sA[SWZ(row, col8 * 2)]) = o;
  }

  bf8 B1[2][4], B2[2][4];
#pragma unroll
  for (int nt = 0; nt < 2; ++nt)
#pragma unroll
    for (int kk = 0; kk < 4; ++kk) {
      int f = (2 * wv + nt) * 4 + kk;
      B1[nt][kk] = *reinterpret_cast<const bf8*>(&w1aP[(f * 64 + l) * 8]);
      B2[nt][kk] = *reinterpret_cast<const bf8*>(&w1bP[(f * 64 + l) * 8]);
    }

  __syncthreads();

  // layer 1
  f32x4 acc[4][2];
  float bias[2];
#pragma unroll
  for (int nt = 0; nt < 2; ++nt) bias[nt] = b1a[(2 * wv + nt) * 16 + (l & 15)];
#pragma unroll
  for (int mt = 0; mt < 4; ++mt)
#pragma unroll
    for (int nt = 0; nt < 2; ++nt)
      acc[mt][nt] = (f32x4){bias[nt], bias[nt], bias[nt], bias[nt]};

#pragma unroll
  for (int kk = 0; kk < 4; ++kk)
#pragma unroll
    for (int mt = 0; mt < 4; ++mt) {
      int rowi = mt * 16 + (l & 15);
      int kByte = (kk * 32 + (l >> 4) * 8) * 2;
      bf8 a = *reinterpret_cast<const bf8*>(&sA[SWZ(rowi, kByte)]);
#pragma unroll
      for (int nt = 0; nt < 2; ++nt)
        acc[mt][nt] = __builtin_amdgcn_mfma_f32_16x16x32_bf16(a, B1[nt][kk],
                                                              acc[mt][nt], 0, 0, 0);
    }
  __syncthreads();  // all sA reads done

  // hidden -> sA
#pragma unroll
  for (int mt = 0; mt < 4; ++mt)
#pragma unroll
    for (int nt = 0; nt < 2; ++nt) {
      int colb = ((2 * wv + nt) * 16 + (l & 15)) * 2;
#pragma unroll
      for (int i = 0; i < 4; ++i) {
        int rowi = mt * 16 + (l >> 4) * 4 + i;
        *reinterpret_cast<__hip_bfloat16*>(&sA[SWZ(rowi, colb)]) =
            __float2bfloat16(fmaxf(acc[mt][nt][i], 0.f));
      }
    }
  __syncthreads();

  // layer 2
#pragma unroll
  for (int nt = 0; nt < 2; ++nt) bias[nt] = b1b[(2 * wv + nt) * 16 + (l & 15)];
#pragma unroll
  for (int mt = 0; mt < 4; ++mt)
#pragma unroll
    for (int nt = 0; nt < 2; ++nt)
      acc[mt][nt] = (f32x4){bias[nt], bias[nt], bias[nt], bias[nt]};

#pragma unroll
  for (int kk = 0; kk < 4; ++kk)
#pragma unroll
    for (int mt = 0; mt < 4; ++mt) {
      int rowi = mt * 16 + (l & 15);
      int kByte = (kk * 32 + (l >> 4) * 8) * 2;
      bf8 a = *reinterpret_cast<const bf8*>(&sA[SWZ(rowi, kByte)]);
#pragma unroll
      for (int nt = 0; nt < 2; ++nt)
        acc[mt][nt] = __builtin_amdgcn_mfma_f32_16x16x32_bf16(a, B2[nt][kk],
                                                              acc[mt][nt], 0, 0, 0);
    }
  __syncthreads();  // all layer-2 sA reads done

  // act(out) -> sA (bf16); last conv keeps raw (no relu)
#pragma unroll
  for (int mt = 0; mt < 4; ++mt)
#pragma unroll
    for (int nt = 0; nt < 2; ++nt) {
      int colb = ((2 * wv + nt) * 16 + (l & 15)) * 2;
#pragma unroll
      for (int i = 0; i < 4; ++i) {
        int rowi = mt * 16 + (l >> 4) * 4 + i;
        float t = acc[mt][nt][i];
        if (!is_last) t = fmaxf(t, 0.f);
        *reinterpret_cast<__hip_bfloat16*>(&sA[SWZ(rowi, colb)]) =
            __float2bfloat16(t);
      }
    }
  __syncthreads();

  // vector epilogue: nh = hb + t; last conv -> f32 d_out, else -> hb
#pragma unroll
  for (int i = 0; i < 4; ++i) {
    int c = tid + i * 256;
    int row = c >> 4, col8 = (c & 15) * 8;
    int gr = r0 + row;
    if (gr < N_NODES) {
      s8v tv = *reinterpret_cast<const s8v*>(&sA[SWZ(row, col8 * 2)]);
      s8v hh = *reinterpret_cast<const s8v*>(&hb[(size_t)gr * HDIM + col8]);
      if (is_last) {
        f4 o0, o1;
#pragma unroll
        for (int q = 0; q < 4; ++q) o0[q] = bf2f(hh[q]) + bf2f(tv[q]);
#pragma unroll
        for (int q = 0; q < 4; ++q) o1[q] = bf2f(hh[q + 4]) + bf2f(tv[q + 4]);
        *reinterpret_cast<f4*>(&hout[(size_t)gr * HDIM + col8]) = o0;
        *reinterpret_cast<f4*>(&hout[(size_t)gr * HDIM + col8 + 4]) = o1;
      } else {
        s8v o;
#pragma unroll
        for (int q = 0; q < 8; ++q) o[q] = f2bf(bf2f(hh[q]) + bf2f(tv[q]));
        *reinterpret_cast<s8v*>(&hb[(size_t)gr * HDIM + col8]) = o;
      }
    }
  }
}

// ---------------- launch --------------------------------------------------------

extern "C" void kernel_launch(void* const* d_in, const int* in_sizes, int n_in,
                              void* d_out, int out_size, void* d_ws, size_t ws_size,
                              hipStream_t stream) {
  const float* z = (const float*)d_in[0];
  const int* ei = (const int*)d_in[1];
  const float* attr = (const float*)d_in[2];
  const float* elen = (const float*)d_in[3];
  const float* w0a = (const float*)d_in[4];
  const float* b0a = (const float*)d_in[5];
  const float* w0b = (const float*)d_in[6];
  const float* b0b = (const float*)d_in[7];
  const float* w1a = (const float*)d_in[8];
  const float* b1a = (const float*)d_in[9];
  const float* w1b = (const float*)d_in[10];
  const float* b1b = (const float*)d_in[11];
  const float* w2a = (const float*)d_in[12];
  const float* b2a = (const float*)d_in[13];
  const float* w2b = (const float*)d_in[14];
  const float* b2b = (const float*)d_in[15];

  float* hout = (float*)d_out;

  char* ws = (char*)d_ws;
  size_t off = 0;
  __hip_bfloat16* Wp = (__hip_bfloat16*)(ws + off);
  off += (size_t)WP_CAP * HDIM * 2;           // 184.3 MB
  __hip_bfloat16* agg_b = (__hip_bfloat16*)(ws + off);
  off += (size_t)N_NODES * HDIM * 2;          // 12.8 MB
  __hip_bfloat16* hb = (__hip_bfloat16*)(ws + off);
  off += (size_t)N_NODES * HDIM * 2;          // 12.8 MB
  int* esrc2 = (int*)(ws + off);
  off += (size_t)N_EDGES * 4;                 // 3.2 MB
  int* uedge = (int*)(ws + off);
  off += (size_t)WP_CAP * 4;                  // 2.88 MB
  int* rank = (int*)(ws + off);
  off += (size_t)N_EDGES * 4;                 // 3.2 MB
  int* urow = (int*)(ws + off);
  off += (size_t)(N_NODES + 64) * 4;
  int* mrow = (int*)(ws + off);
  off += (size_t)(N_NODES + 64) * 4;
  // zero-init region: [ucnt][mcnt] — one memset
  int* ucnt = (int*)(ws + off);
  off += (size_t)N_NODES * 4;
  int* mcnt = (int*)(ws + off);
  off += (size_t)N_NODES * 4;
  int* bsum = (int*)(ws + off);
  off += (size_t)(2 * NB_SCAN + 8) * 4;
  int* boff = (int*)(ws + off);
  off += (size_t)(2 * NB_SCAN + 8) * 4;
  __hip_bfloat16* wPk = (__hip_bfloat16*)(ws + off);  // [w2a|w2b|w1a|w1b|w0b]
  off += (size_t)5 * HDIM * HDIM * 2;                 // 160 KB
  __hip_bfloat16* w2aP = wPk;
  __hip_bfloat16* w2bP = wPk + 16384;
  __hip_bfloat16* w1aP = wPk + 2 * 16384;
  __hip_bfloat16* w1bP = wPk + 3 * 16384;
  __hip_bfloat16* w0bP = wPk + 4 * 16384;

  const int* src = ei;
  const int* dst = ei + N_EDGES;

  // split CSR build (single atomic pass; mask packed into rank)
  hipMemsetAsync(ucnt, 0, (size_t)(2 * N_NODES) * 4, stream);
  k_count<<<(N_EDGES + 255) / 256, 256, 0, stream>>>(dst, elen, ucnt, mcnt, rank);
  k_scan_local<<<2 * NB_SCAN, 256, 0, stream>>>(ucnt, mcnt, urow, mrow, bsum);
  k_scan_top<<<1, 256, 0, stream>>>(bsum, boff);
  k_scan_add_repack<<<2 * NB_SCAN + 40, 256, 0, stream>>>(
      urow, mrow, boff, w2a, w2b, w1a, w1b, w0b, wPk);
  k_scatter<<<(N_EDGES + 255) / 256, 256, 0, stream>>>(src, dst, urow, mrow, rank,
                                                       esrc2, uedge);

  // fused node-embedding + edge-gate dispatch
  k_emb_gate_mfma<<<NB_EMB + (N_EDGES + 63) / 64, 256, 0, stream>>>(
      z, w0a, b0a, w0bP, b0b, hb, attr, w2aP, b2a, w2bP, b2b, uedge,
      &urow[N_NODES], Wp);

  // convs (bf16 hb master; final conv writes f32 d_out)
  for (int conv = 0; conv < 3; ++conv) {
    k_aggregate<<<(N_NODES + 15) / 16, 256, 0, stream>>>(hb, Wp, urow, mrow, esrc2,
                                                         agg_b);
    k_update_mfma<<<(N_NODES + 63) / 64, 256, 0, stream>>>(
        agg_b, w1aP, b1a, w1bP, b1b, hb, hout, conv == 2 ? 1 : 0);
  }
}

// Round 13
// 347.202 us; speedup vs baseline: 1.1503x; 1.0072x over previous
//
#include <hip/hip_runtime.h>
#include <hip/hip_bf16.h>

#define N_NODES 50000
#define N_EDGES 800000
#define HDIM 128
#define NCH 5
#define NB_SCAN ((N_NODES + 255) / 256)  // 196
#define NB_CNT ((N_EDGES + 255) / 256)   // 3125
#define NB_EMB ((N_NODES + 63) / 64)     // 782
#define NB_ZERO ((2 * N_NODES + 255) / 256)  // 391
#define CUTOFF 10.0f
#define WP_CAP 720000  // Wp row capacity; expected ~400k unmasked (guarded)

typedef float f4 __attribute__((ext_vector_type(4)));
typedef short bf8 __attribute__((ext_vector_type(8)));    // 8 bf16 = MFMA A/B frag
typedef short s8v __attribute__((ext_vector_type(8)));    // raw 8x bf16 bits
typedef float f32x4 __attribute__((ext_vector_type(4)));  // MFMA C/D frag

struct __align__(8) b16x4 { __hip_bfloat16 v[4]; };
struct __align__(16) b16x8 { __hip_bfloat16 v[8]; };

__device__ __forceinline__ float bf2f(short u) {
  return __uint_as_float(((unsigned)(unsigned short)u) << 16);
}
__device__ __forceinline__ short f2bf(float f) {
  return (short)__bfloat16_as_ushort(__float2bfloat16(f));
}

#define SWZ(row, colByte) ((row) * 256 + ((colByte) ^ (((row) & 7) << 4)))

// ---------------- zero cnt arrays + repack 5 weight mats (one launch) -----------
// blocks [0, NB_ZERO): zero ucnt|mcnt (contiguous)
// blocks [NB_ZERO, NB_ZERO+40): wp[mat*16384 + ((jt*4+kk)*64 + l)*8 + j]
//   = bf16( w[(kk*32 + (l>>4)*8 + j)*128 + jt*16 + (l&15)] )

__global__ __launch_bounds__(256) void k_zero_repack(
    int* __restrict__ zeroBase, const float* __restrict__ w2a,
    const float* __restrict__ w2b, const float* __restrict__ w1a,
    const float* __restrict__ w1b, const float* __restrict__ w0b,
    __hip_bfloat16* __restrict__ wp) {
  int b = blockIdx.x, tid = threadIdx.x;
  if (b < NB_ZERO) {
    int i = b * 256 + tid;
    if (i < 2 * N_NODES) zeroBase[i] = 0;
  } else {
    int gid = b - NB_ZERO;  // 0..39
    int mat = gid >> 3;
    const float* w = (mat == 0) ? w2a
                     : (mat == 1) ? w2b
                     : (mat == 2) ? w1a
                     : (mat == 3) ? w1b : w0b;
    int idx = (gid & 7) * 256 + tid;  // 0..2047 within mat
    int l = idx & 63;
    int f = idx >> 6;
    int kk = f & 3, jt = f >> 2;
    int col = jt * 16 + (l & 15);
    int kb = kk * 32 + (l >> 4) * 8;
    b16x8 o;
#pragma unroll
    for (int j = 0; j < 8; ++j) o.v[j] = __float2bfloat16(w[(kb + j) * HDIM + col]);
    *reinterpret_cast<b16x8*>(&wp[(size_t)mat * 16384 + idx * 8]) = o;
  }
}

// ---------------- fused CSR-count + node-embedding dispatch ---------------------
// blocks [0, NB_CNT): count (rank[i] = (per-dst rank << 1) | unmasked_flag)
// blocks [NB_CNT, NB_CNT+NB_EMB): hb = bf16(relu(z@w0a+b0a)@w0b+b0b), L2 via MFMA

__global__ __launch_bounds__(256) void k_count_emb(
    const int* __restrict__ dst, const float* __restrict__ elen,
    int* __restrict__ ucnt, int* __restrict__ mcnt, int* __restrict__ rank,
    const float* __restrict__ z, const float* __restrict__ w0a,
    const float* __restrict__ b0a, const __hip_bfloat16* __restrict__ w0bP,
    const float* __restrict__ b0b, __hip_bfloat16* __restrict__ hb) {
  const int tid = threadIdx.x;

  if (blockIdx.x < NB_CNT) {
    // ---- CSR count
    int i = blockIdx.x * 256 + tid;
    if (i < N_EDGES) {
      int d = dst[i];
      int m = (elen[i] <= CUTOFF) ? 1 : 0;
      int r = atomicAdd(m ? &ucnt[d] : &mcnt[d], 1);
      rank[i] = (r << 1) | m;
    }
    return;
  }

  // ---- node embedding
  __shared__ char sA[64 * 256];  // 64 x 128 bf16, swizzled
  __shared__ float zs[64][NCH];
  __shared__ float w0as[NCH][HDIM];
  __shared__ float b0as[HDIM];
  const int wv = tid >> 6, l = tid & 63;
  const int r0 = (blockIdx.x - NB_CNT) * 64;

  for (int i = tid; i < NCH * HDIM; i += 256) w0as[i / HDIM][i % HDIM] = w0a[i];
  if (tid < HDIM) b0as[tid] = b0a[tid];
  for (int i = tid; i < 64 * NCH; i += 256) {
    int r = i / NCH, c = i % NCH;
    int gr = r0 + r;
    zs[r][c] = (gr < N_NODES) ? z[(size_t)gr * NCH + c] : 0.f;
  }

  bf8 B0[2][4];
#pragma unroll
  for (int nt = 0; nt < 2; ++nt)
#pragma unroll
    for (int kk = 0; kk < 4; ++kk) {
      int f = (2 * wv + nt) * 4 + kk;
      B0[nt][kk] = *reinterpret_cast<const bf8*>(&w0bP[(f * 64 + l) * 8]);
    }

  __syncthreads();

  // layer 1: hidden = relu(z@w0a + b0a) -> sA bf16
#pragma unroll
  for (int i = 0; i < 4; ++i) {
    int c = tid + i * 256;
    int row = c >> 4, col8 = (c & 15) * 8;
    float h8[8];
#pragma unroll
    for (int q = 0; q < 8; ++q) h8[q] = b0as[col8 + q];
#pragma unroll
    for (int c5 = 0; c5 < NCH; ++c5) {
      float zv = zs[row][c5];
#pragma unroll
      for (int q = 0; q < 8; ++q) h8[q] += zv * w0as[c5][col8 + q];
    }
    s8v o;
#pragma unroll
    for (int q = 0; q < 8; ++q) o[q] = f2bf(fmaxf(h8[q], 0.f));
    *reinterpret_cast<s8v*>(&sA[SWZ(row, col8 * 2)]) = o;
  }
  __syncthreads();

  // layer 2 via MFMA
  f32x4 acc[4][2];
  float bias[2];
#pragma unroll
  for (int nt = 0; nt < 2; ++nt) bias[nt] = b0b[(2 * wv + nt) * 16 + (l & 15)];
#pragma unroll
  for (int mt = 0; mt < 4; ++mt)
#pragma unroll
    for (int nt = 0; nt < 2; ++nt)
      acc[mt][nt] = (f32x4){bias[nt], bias[nt], bias[nt], bias[nt]};

#pragma unroll
  for (int kk = 0; kk < 4; ++kk)
#pragma unroll
    for (int mt = 0; mt < 4; ++mt) {
      int rowi = mt * 16 + (l & 15);
      int kByte = (kk * 32 + (l >> 4) * 8) * 2;
      bf8 a = *reinterpret_cast<const bf8*>(&sA[SWZ(rowi, kByte)]);
#pragma unroll
      for (int nt = 0; nt < 2; ++nt)
        acc[mt][nt] = __builtin_amdgcn_mfma_f32_16x16x32_bf16(a, B0[nt][kk],
                                                              acc[mt][nt], 0, 0, 0);
    }
  __syncthreads();

  // out -> sA bf16
#pragma unroll
  for (int mt = 0; mt < 4; ++mt)
#pragma unroll
    for (int nt = 0; nt < 2; ++nt) {
      int colb = ((2 * wv + nt) * 16 + (l & 15)) * 2;
#pragma unroll
      for (int i = 0; i < 4; ++i) {
        int rowi = mt * 16 + (l >> 4) * 4 + i;
        *reinterpret_cast<__hip_bfloat16*>(&sA[SWZ(rowi, colb)]) =
            __float2bfloat16(acc[mt][nt][i]);
      }
    }
  __syncthreads();

  // vector store -> hb
#pragma unroll
  for (int i = 0; i < 4; ++i) {
    int c = tid + i * 256;
    int row = c >> 4, col8 = (c & 15) * 8;
    int gr = r0 + row;
    if (gr < N_NODES) {
      s8v v = *reinterpret_cast<const s8v*>(&sA[SWZ(row, col8 * 2)]);
      *reinterpret_cast<s8v*>(&hb[(size_t)gr * HDIM + col8]) = v;
    }
  }
}

// joint u+m local scan: blocks [0,NB) -> ucnt/urow, [NB,2NB) -> mcnt/mrow
__global__ __launch_bounds__(256) void k_scan_local(
    const int* __restrict__ ucnt, const int* __restrict__ mcnt,
    int* __restrict__ urow, int* __restrict__ mrow, int* __restrict__ bsum) {
  __shared__ int buf[256];
  int b = blockIdx.x, tid = threadIdx.x;
  const int* cnt = (b < NB_SCAN) ? ucnt : mcnt;
  int* row = (b < NB_SCAN) ? urow : mrow;
  int i = ((b < NB_SCAN) ? b : b - NB_SCAN) * 256 + tid;
  int v = (i < N_NODES) ? cnt[i] : 0;
  buf[tid] = v;
  __syncthreads();
  for (int off = 1; off < 256; off <<= 1) {
    int t = (tid >= off) ? buf[tid - off] : 0;
    __syncthreads();
    buf[tid] += t;
    __syncthreads();
  }
  if (i < N_NODES) row[i] = buf[tid] - v;  // local exclusive
  if (tid == 255) bsum[b] = buf[255];
}

// joint top scan over 2*NB block sums (m prefixes come out pre-offset by nUm)
__global__ __launch_bounds__(256) void k_scan_top(const int* __restrict__ bsum,
                                                  int* __restrict__ boff) {
  __shared__ int buf[256];
  int tid = threadIdx.x;
  int run = 0;
  for (int base = 0; base < 2 * NB_SCAN; base += 256) {
    int i = base + tid;
    int v = (i < 2 * NB_SCAN) ? bsum[i] : 0;
    buf[tid] = v;
    __syncthreads();
    for (int off = 1; off < 256; off <<= 1) {
      int t = (tid >= off) ? buf[tid - off] : 0;
      __syncthreads();
      buf[tid] += t;
      __syncthreads();
    }
    if (i < 2 * NB_SCAN) boff[i] = run + buf[tid] - v;
    run += buf[255];
    __syncthreads();
  }
  if (tid == 0) boff[2 * NB_SCAN] = run;  // = N_EDGES
}

__global__ __launch_bounds__(256) void k_scan_add(int* __restrict__ urow,
                                                  int* __restrict__ mrow,
                                                  const int* __restrict__ boff) {
  int b = blockIdx.x, tid = threadIdx.x;
  int* row = (b < NB_SCAN) ? urow : mrow;
  int i = ((b < NB_SCAN) ? b : b - NB_SCAN) * 256 + tid;
  if (i < N_NODES) row[i] += boff[b];
  if (tid == 0 && b == 0) urow[N_NODES] = boff[NB_SCAN];            // nUm
  if (tid == 0 && b == NB_SCAN) mrow[N_NODES] = boff[2 * NB_SCAN];  // N_EDGES
}

// atomic-free scatter: slot = row[dst] + rank (mask decoded from rank low bit)
__global__ void k_scatter(const int* __restrict__ src, const int* __restrict__ dst,
                          const int* __restrict__ urow, const int* __restrict__ mrow,
                          const int* __restrict__ rank, int* __restrict__ esrc2,
                          int* __restrict__ uedge) {
  int i = blockIdx.x * blockDim.x + threadIdx.x;
  if (i < N_EDGES) {
    int d = dst[i];
    int rm = rank[i];
    int r = rm >> 1;
    if (rm & 1) {
      int p = urow[d] + r;
      esrc2[p] = src[i];
      if (p < WP_CAP) uedge[p] = i;
    } else {
      int q = mrow[d] + r;
      esrc2[q] = src[i];
    }
  }
}

// ---------------- edge gate via MFMA, uCSR-slot order; single LDS tile ---------

__global__ __launch_bounds__(256) void k_edge_gate_mfma(
    const float* __restrict__ attr, const __hip_bfloat16* __restrict__ w2aP,
    const float* __restrict__ b2a, const __hip_bfloat16* __restrict__ w2bP,
    const float* __restrict__ b2b, const int* __restrict__ uedge,
    const int* __restrict__ nUmPtr, __hip_bfloat16* __restrict__ Wp) {
  __shared__ char sA[64 * 256];  // 64 x 128 bf16, swizzled (reused 3x)
  __shared__ int sEid[64];
  const int tid = threadIdx.x;
  const int wv = tid >> 6, l = tid & 63;
  const int e0 = blockIdx.x * 64;
  const int nUm = min(nUmPtr[0], WP_CAP);
  if (e0 >= nUm) return;

  if (tid < 64) {
    int idx = e0 + tid;
    sEid[tid] = uedge[(idx < nUm) ? idx : (nUm - 1)];
  }
  __syncthreads();

  // stage attr rows (gathered by edge id) -> sA bf16
#pragma unroll
  for (int i = 0; i < 8; ++i) {
    int c = tid + i * 256;
    int row = c >> 5, col4 = (c & 31) * 4;
    f4 v = *reinterpret_cast<const f4*>(&attr[(size_t)sEid[row] * HDIM + col4]);
    b16x4 o;
    o.v[0] = __float2bfloat16(v[0]);
    o.v[1] = __float2bfloat16(v[1]);
    o.v[2] = __float2bfloat16(v[2]);
    o.v[3] = __float2bfloat16(v[3]);
    *reinterpret_cast<b16x4*>(&sA[SWZ(row, col4 * 2)]) = o;
  }

  bf8 B1[2][4], B2[2][4];
#pragma unroll
  for (int nt = 0; nt < 2; ++nt)
#pragma unroll
    for (int kk = 0; kk < 4; ++kk) {
      int f = (2 * wv + nt) * 4 + kk;
      B1[nt][kk] = *reinterpret_cast<const bf8*>(&w2aP[(f * 64 + l) * 8]);
      B2[nt][kk] = *reinterpret_cast<const bf8*>(&w2bP[(f * 64 + l) * 8]);
    }

  __syncthreads();

  // layer 1
  f32x4 acc[4][2];
  float bias[2];
#pragma unroll
  for (int nt = 0; nt < 2; ++nt) bias[nt] = b2a[(2 * wv + nt) * 16 + (l & 15)];
#pragma unroll
  for (int mt = 0; mt < 4; ++mt)
#pragma unroll
    for (int nt = 0; nt < 2; ++nt)
      acc[mt][nt] = (f32x4){bias[nt], bias[nt], bias[nt], bias[nt]};

#pragma unroll
  for (int kk = 0; kk < 4; ++kk)
#pragma unroll
    for (int mt = 0; mt < 4; ++mt) {
      int row = mt * 16 + (l & 15);
      int kByte = (kk * 32 + (l >> 4) * 8) * 2;
      bf8 a = *reinterpret_cast<const bf8*>(&sA[SWZ(row, kByte)]);
#pragma unroll
      for (int nt = 0; nt < 2; ++nt)
        acc[mt][nt] = __builtin_amdgcn_mfma_f32_16x16x32_bf16(a, B1[nt][kk],
                                                              acc[mt][nt], 0, 0, 0);
    }
  __syncthreads();  // all sA reads done; safe to overwrite

  // hidden = relu(acc) -> sA
#pragma unroll
  for (int mt = 0; mt < 4; ++mt)
#pragma unroll
    for (int nt = 0; nt < 2; ++nt) {
      int colb = ((2 * wv + nt) * 16 + (l & 15)) * 2;
#pragma unroll
      for (int i = 0; i < 4; ++i) {
        int row = mt * 16 + (l >> 4) * 4 + i;
        *reinterpret_cast<__hip_bfloat16*>(&sA[SWZ(row, colb)]) =
            __float2bfloat16(fmaxf(acc[mt][nt][i], 0.f));
      }
    }
  __syncthreads();

  // layer 2
#pragma unroll
  for (int nt = 0; nt < 2; ++nt) bias[nt] = b2b[(2 * wv + nt) * 16 + (l & 15)];
#pragma unroll
  for (int mt = 0; mt < 4; ++mt)
#pragma unroll
    for (int nt = 0; nt < 2; ++nt)
      acc[mt][nt] = (f32x4){bias[nt], bias[nt], bias[nt], bias[nt]};

#pragma unroll
  for (int kk = 0; kk < 4; ++kk)
#pragma unroll
    for (int mt = 0; mt < 4; ++mt) {
      int row = mt * 16 + (l & 15);
      int kByte = (kk * 32 + (l >> 4) * 8) * 2;
      bf8 a = *reinterpret_cast<const bf8*>(&sA[SWZ(row, kByte)]);
#pragma unroll
      for (int nt = 0; nt < 2; ++nt)
        acc[mt][nt] = __builtin_amdgcn_mfma_f32_16x16x32_bf16(a, B2[nt][kk],
                                                              acc[mt][nt], 0, 0, 0);
    }
  __syncthreads();  // all layer-2 sA reads done

  // output -> sA
#pragma unroll
  for (int mt = 0; mt < 4; ++mt)
#pragma unroll
    for (int nt = 0; nt < 2; ++nt) {
      int colb = ((2 * wv + nt) * 16 + (l & 15)) * 2;
#pragma unroll
      for (int i = 0; i < 4; ++i) {
        int row = mt * 16 + (l >> 4) * 4 + i;
        *reinterpret_cast<__hip_bfloat16*>(&sA[SWZ(row, colb)]) =
            __float2bfloat16(acc[mt][nt][i]);
      }
    }
  __syncthreads();

  // contiguous store: Wp rows e0..e0+63, tail-guarded
#pragma unroll
  for (int i = 0; i < 4; ++i) {
    int c = tid + i * 256;
    int row = c >> 4, colc = c & 15;
    if (e0 + row < nUm) {
      b16x8 v = *reinterpret_cast<const b16x8*>(&sA[SWZ(row, colc * 16)]);
      *reinterpret_cast<b16x8*>(&Wp[(size_t)(e0 + row) * HDIM + colc * 8]) = v;
    }
  }
}

// ---------------- aggregate batch helpers (order-preserving) --------------------

__device__ __forceinline__ void agg_batch_u(
    const __hip_bfloat16* __restrict__ hb, const __hip_bfloat16* __restrict__ Wp,
    int idx, int p0, int cnt, int grpBase, int c8, float s[8]) {
  for (int j = 0; j < cnt; j += 4) {
    s8v hv[4], wv[4];
#pragma unroll
    for (int t = 0; t < 4; ++t) {
      int sr = __shfl(idx, grpBase + j + t, 64);
      if (j + t < cnt) {
        hv[t] = *reinterpret_cast<const s8v*>(&hb[(size_t)sr * HDIM + c8]);
        wv[t] = *reinterpret_cast<const s8v*>(&Wp[(size_t)(p0 + j + t) * HDIM + c8]);
      } else {
        hv[t] = (s8v)0;
        wv[t] = (s8v)0;
      }
    }
#pragma unroll
    for (int t = 0; t < 4; ++t)
#pragma unroll
      for (int q = 0; q < 8; ++q)
        s[q] += fmaxf(bf2f(hv[t][q]) + bf2f(wv[t][q]), 0.f);
  }
}

__device__ __forceinline__ void agg_batch_m(
    const __hip_bfloat16* __restrict__ hb, int idx, int cnt, int grpBase, int c8,
    float s[8]) {
  for (int j = 0; j < cnt; j += 4) {
    s8v hv[4];
#pragma unroll
    for (int t = 0; t < 4; ++t) {
      int sr = __shfl(idx, grpBase + j + t, 64);
      if (j + t < cnt)
        hv[t] = *reinterpret_cast<const s8v*>(&hb[(size_t)sr * HDIM + c8]);
      else
        hv[t] = (s8v)0;
    }
#pragma unroll
    for (int t = 0; t < 4; ++t)
#pragma unroll
      for (int q = 0; q < 8; ++q) s[q] += fmaxf(bf2f(hv[t][q]), 0.f);
  }
}

// ---------------- aggregate: dual-chain prefetch (u + m idx loads overlap) ------
// agg_b[n] = bf16( sum_u relu(hb[src]+Wp[p]) + sum_m relu(hb[src]) )

__global__ __launch_bounds__(256) void k_aggregate(
    const __hip_bfloat16* __restrict__ hb, const __hip_bfloat16* __restrict__ Wp,
    const int* __restrict__ urow, const int* __restrict__ mrow,
    const int* __restrict__ esrc2, __hip_bfloat16* __restrict__ agg_b) {
  int tid = threadIdx.x;
  int node = blockIdx.x * 16 + (tid >> 4);
  if (node >= N_NODES) return;
  const int lane16 = tid & 15;
  const int grpBase = tid & 48;  // group's base lane within the 64-lane wave
  const int c8 = lane16 * 8;

  int ub = urow[node], ueFull = urow[node + 1];
  int ue = min(ueFull, WP_CAP);
  int mb = mrow[node], me = mrow[node + 1];
  int cntU0 = min(ue - ub, 16);
  int cntM0 = min(me - mb, 16);
  // both first-batch index loads issued before any gather (chains overlap)
  int idxU = (lane16 < cntU0) ? esrc2[ub + lane16] : 0;
  int idxM = (lane16 < cntM0) ? esrc2[mb + lane16] : 0;

  float s[8];
#pragma unroll
  for (int q = 0; q < 8; ++q) s[q] = 0.f;

  // ---- unmasked edges: hb gather + Wp stream
  if (cntU0 > 0) agg_batch_u(hb, Wp, idxU, ub, cntU0, grpBase, c8, s);
  for (int p0 = ub + 16; p0 < ue; p0 += 16) {
    int cnt = min(ue - p0, 16);
    int idx = (lane16 < cnt) ? esrc2[p0 + lane16] : 0;
    agg_batch_u(hb, Wp, idx, p0, cnt, grpBase, c8, s);
  }
  for (int p = ue; p < ueFull; ++p) {  // WP_CAP overflow guard (never in practice)
    int sr = esrc2[p];
    s8v hv = *reinterpret_cast<const s8v*>(&hb[(size_t)sr * HDIM + c8]);
#pragma unroll
    for (int q = 0; q < 8; ++q) s[q] += fmaxf(bf2f(hv[q]), 0.f);
  }

  // ---- masked edges: relu(hb) only
  if (cntM0 > 0) agg_batch_m(hb, idxM, cntM0, grpBase, c8, s);
  for (int p0 = mb + 16; p0 < me; p0 += 16) {
    int cnt = min(me - p0, 16);
    int idx = (lane16 < cnt) ? esrc2[p0 + lane16] : 0;
    agg_batch_m(hb, idx, cnt, grpBase, c8, s);
  }

  s8v o;
#pragma unroll
  for (int q = 0; q < 8; ++q) o[q] = f2bf(s[q]);
  *reinterpret_cast<s8v*>(&agg_b[(size_t)node * HDIM + c8]) = o;
}

// ---------------- update via MFMA: hb += act(MLP1(agg + hb)); last -> f32 out ---
// Vectorized epilogue: act(out) routed through sA, hb re-read as 16B chunks.

__global__ __launch_bounds__(256) void k_update_mfma(
    const __hip_bfloat16* __restrict__ agg_b,
    const __hip_bfloat16* __restrict__ w1aP, const float* __restrict__ b1a,
    const __hip_bfloat16* __restrict__ w1bP, const float* __restrict__ b1b,
    __hip_bfloat16* __restrict__ hb, float* __restrict__ hout, int is_last) {
  __shared__ char sA[64 * 256];  // 64 x 128 bf16, swizzled (reused)
  const int tid = threadIdx.x;
  const int wv = tid >> 6, l = tid & 63;
  const int r0 = blockIdx.x * 64;

  // stage bf16(agg + hb) -> sA   (1024 16B-chunks)
#pragma unroll
  for (int i = 0; i < 4; ++i) {
    int c = tid + i * 256;
    int row = c >> 4, col8 = (c & 15) * 8;
    int gr = r0 + row;
    s8v o = (s8v)0;
    if (gr < N_NODES) {
      s8v a = *reinterpret_cast<const s8v*>(&agg_b[(size_t)gr * HDIM + col8]);
      s8v hh = *reinterpret_cast<const s8v*>(&hb[(size_t)gr * HDIM + col8]);
#pragma unroll
      for (int q = 0; q < 8; ++q) o[q] = f2bf(bf2f(a[q]) + bf2f(hh[q]));
    }
    *reinterpret_cast<s8v*>(&sA[SWZ(row, col8 * 2)]) = o;
  }

  bf8 B1[2][4], B2[2][4];
#pragma unroll
  for (int nt = 0; nt < 2; ++nt)
#pragma unroll
    for (int kk = 0; kk < 4; ++kk) {
      int f = (2 * wv + nt) * 4 + kk;
      B1[nt][kk] = *reinterpret_cast<const bf8*>(&w1aP[(f * 64 + l) * 8]);
      B2[nt][kk] = *reinterpret_cast<const bf8*>(&w1bP[(f * 64 + l) * 8]);
    }

  __syncthreads();

  // layer 1
  f32x4 acc[4][2];
  float bias[2];
#pragma unroll
  for (int nt = 0; nt < 2; ++nt) bias[nt] = b1a[(2 * wv + nt) * 16 + (l & 15)];
#pragma unroll
  for (int mt = 0; mt < 4; ++mt)
#pragma unroll
    for (int nt = 0; nt < 2; ++nt)
      acc[mt][nt] = (f32x4){bias[nt], bias[nt], bias[nt], bias[nt]};

#pragma unroll
  for (int kk = 0; kk < 4; ++kk)
#pragma unroll
    for (int mt = 0; mt < 4; ++mt) {
      int rowi = mt * 16 + (l & 15);
      int kByte = (kk * 32 + (l >> 4) * 8) * 2;
      bf8 a = *reinterpret_cast<const bf8*>(&sA[SWZ(rowi, kByte)]);
#pragma unroll
      for (int nt = 0; nt < 2; ++nt)
        acc[mt][nt] = __builtin_amdgcn_mfma_f32_16x16x32_bf16(a, B1[nt][kk],
                                                              acc[mt][nt], 0, 0, 0);
    }
  __syncthreads();  // all sA reads done

  // hidden -> sA
#pragma unroll
  for (int mt = 0; mt < 4; ++mt)
#pragma unroll
    for (int nt = 0; nt < 2; ++nt) {
      int colb = ((2 * wv + nt) * 16 + (l & 15)) * 2;
#pragma unroll
      for (int i = 0; i < 4; ++i) {
        int rowi = mt * 16 + (l >> 4) * 4 + i;
        *reinterpret_cast<__hip_bfloat16*>(&sA[SWZ(rowi, colb)]) =
            __float2bfloat16(fmaxf(acc[mt][nt][i], 0.f));
      }
    }
  __syncthreads();

  // layer 2
#pragma unroll
  for (int nt = 0; nt < 2; ++nt) bias[nt] = b1b[(2 * wv + nt) * 16 + (l & 15)];
#pragma unroll
  for (int mt = 0; mt < 4; ++mt)
#pragma unroll
    for (int nt = 0; nt < 2; ++nt)
      acc[mt][nt] = (f32x4){bias[nt], bias[nt], bias[nt], bias[nt]};

#pragma unroll
  for (int kk = 0; kk < 4; ++kk)
#pragma unroll
    for (int mt = 0; mt < 4; ++mt) {
      int rowi = mt * 16 + (l & 15);
      int kByte = (kk * 32 + (l >> 4) * 8) * 2;
      bf8 a = *reinterpret_cast<const bf8*>(&sA[SWZ(rowi, kByte)]);
#pragma unroll
      for (int nt = 0; nt < 2; ++nt)
        acc[mt][nt] = __builtin_amdgcn_mfma_f32_16x16x32_bf16(a, B2[nt][kk],
                                                              acc[mt][nt], 0, 0, 0);
    }
  __syncthreads();  // all layer-2 sA reads done

  // act(out) -> sA (bf16); last conv keeps raw (no relu)
#pragma unroll
  for (int mt = 0; mt < 4; ++mt)
#pragma unroll
    for (int nt = 0; nt < 2; ++nt) {
      int colb = ((2 * wv + nt) * 16 + (l & 15)) * 2;
#pragma unroll
      for (int i = 0; i < 4; ++i) {
        int rowi = mt * 16 + (l >> 4) * 4 + i;
        float t = acc[mt][nt][i];
        if (!is_last) t = fmaxf(t, 0.f);
        *reinterpret_cast<__hip_bfloat16*>(&sA[SWZ(rowi, colb)]) =
            __float2bfloat16(t);
      }
    }
  __syncthreads();

  // vector epilogue: nh = hb + t; last conv -> f32 d_out, else -> hb
#pragma unroll
  for (int i = 0; i < 4; ++i) {
    int c = tid + i * 256;
    int row = c >> 4, col8 = (c & 15) * 8;
    int gr = r0 + row;
    if (gr < N_NODES) {
      s8v tv = *reinterpret_cast<const s8v*>(&sA[SWZ(row, col8 * 2)]);
      s8v hh = *reinterpret_cast<const s8v*>(&hb[(size_t)gr * HDIM + col8]);
      if (is_last) {
        f4 o0, o1;
#pragma unroll
        for (int q = 0; q < 4; ++q) o0[q] = bf2f(hh[q]) + bf2f(tv[q]);
#pragma unroll
        for (int q = 0; q < 4; ++q) o1[q] = bf2f(hh[q + 4]) + bf2f(tv[q + 4]);
        *reinterpret_cast<f4*>(&hout[(size_t)gr * HDIM + col8]) = o0;
        *reinterpret_cast<f4*>(&hout[(size_t)gr * HDIM + col8 + 4]) = o1;
      } else {
        s8v o;
#pragma unroll
        for (int q = 0; q < 8; ++q) o[q] = f2bf(bf2f(hh[q]) + bf2f(tv[q]));
        *reinterpret_cast<s8v*>(&hb[(size_t)gr * HDIM + col8]) = o;
      }
    }
  }
}

// ---------------- launch --------------------------------------------------------

extern "C" void kernel_launch(void* const* d_in, const int* in_sizes, int n_in,
                              void* d_out, int out_size, void* d_ws, size_t ws_size,
                              hipStream_t stream) {
  const float* z = (const float*)d_in[0];
  const int* ei = (const int*)d_in[1];
  const float* attr = (const float*)d_in[2];
  const float* elen = (const float*)d_in[3];
  const float* w0a = (const float*)d_in[4];
  const float* b0a = (const float*)d_in[5];
  const float* w0b = (const float*)d_in[6];
  const float* b0b = (const float*)d_in[7];
  const float* w1a = (const float*)d_in[8];
  const float* b1a = (const float*)d_in[9];
  const float* w1b = (const float*)d_in[10];
  const float* b1b = (const float*)d_in[11];
  const float* w2a = (const float*)d_in[12];
  const float* b2a = (const float*)d_in[13];
  const float* w2b = (const float*)d_in[14];
  const float* b2b = (const float*)d_in[15];

  float* hout = (float*)d_out;

  char* ws = (char*)d_ws;
  size_t off = 0;
  __hip_bfloat16* Wp = (__hip_bfloat16*)(ws + off);
  off += (size_t)WP_CAP * HDIM * 2;           // 184.3 MB
  __hip_bfloat16* agg_b = (__hip_bfloat16*)(ws + off);
  off += (size_t)N_NODES * HDIM * 2;          // 12.8 MB
  __hip_bfloat16* hb = (__hip_bfloat16*)(ws + off);
  off += (size_t)N_NODES * HDIM * 2;          // 12.8 MB
  int* esrc2 = (int*)(ws + off);
  off += (size_t)N_EDGES * 4;                 // 3.2 MB
  int* uedge = (int*)(ws + off);
  off += (size_t)WP_CAP * 4;                  // 2.88 MB
  int* rank = (int*)(ws + off);
  off += (size_t)N_EDGES * 4;                 // 3.2 MB
  int* urow = (int*)(ws + off);
  off += (size_t)(N_NODES + 64) * 4;
  int* mrow = (int*)(ws + off);
  off += (size_t)(N_NODES + 64) * 4;
  // zero-init region: [ucnt][mcnt] — zeroed by k_zero_repack
  int* ucnt = (int*)(ws + off);
  off += (size_t)N_NODES * 4;
  int* mcnt = (int*)(ws + off);
  off += (size_t)N_NODES * 4;
  int* bsum = (int*)(ws + off);
  off += (size_t)(2 * NB_SCAN + 8) * 4;
  int* boff = (int*)(ws + off);
  off += (size_t)(2 * NB_SCAN + 8) * 4;
  __hip_bfloat16* wPk = (__hip_bfloat16*)(ws + off);  // [w2a|w2b|w1a|w1b|w0b]
  off += (size_t)5 * HDIM * HDIM * 2;                 // 160 KB
  __hip_bfloat16* w2aP = wPk;
  __hip_bfloat16* w2bP = wPk + 16384;
  __hip_bfloat16* w1aP = wPk + 2 * 16384;
  __hip_bfloat16* w1bP = wPk + 3 * 16384;
  __hip_bfloat16* w0bP = wPk + 4 * 16384;

  const int* src = ei;
  const int* dst = ei + N_EDGES;

  // zero cnt arrays + repack all 5 weight mats (one launch)
  k_zero_repack<<<NB_ZERO + 40, 256, 0, stream>>>(ucnt, w2a, w2b, w1a, w1b, w0b,
                                                  wPk);

  // fused CSR-count + node-embedding (emb hides under count's atomics)
  k_count_emb<<<NB_CNT + NB_EMB, 256, 0, stream>>>(dst, elen, ucnt, mcnt, rank, z,
                                                   w0a, b0a, w0bP, b0b, hb);

  // scans + scatter
  k_scan_local<<<2 * NB_SCAN, 256, 0, stream>>>(ucnt, mcnt, urow, mrow, bsum);
  k_scan_top<<<1, 256, 0, stream>>>(bsum, boff);
  k_scan_add<<<2 * NB_SCAN, 256, 0, stream>>>(urow, mrow, boff);
  k_scatter<<<NB_CNT, 256, 0, stream>>>(src, dst, urow, mrow, rank, esrc2, uedge);

  // edge gate in uCSR-slot order (worst-case grid; blocks past nUm exit early)
  k_edge_gate_mfma<<<(N_EDGES + 63) / 64, 256, 0, stream>>>(
      attr, w2aP, b2a, w2bP, b2b, uedge, &urow[N_NODES], Wp);

  // convs (bf16 hb master; final conv writes f32 d_out)
  for (int conv = 0; conv < 3; ++conv) {
    k_aggregate<<<(N_NODES + 15) / 16, 256, 0, stream>>>(hb, Wp, urow, mrow, esrc2,
                                                         agg_b);
    k_update_mfma<<<(N_NODES + 63) / 64, 256, 0, stream>>>(
        agg_b, w1aP, b1a, w1bP, b1b, hb, hout, conv == 2 ? 1 : 0);
  }
}